// Round 6
// baseline (491.173 us; speedup 1.0000x reference)
//
#include <hip/hip_runtime.h>
#include <cstdint>
#include <cstddef>

// ---- problem constants ----
static constexpr int S_LEN = 2048;
static constexpr int HID   = 2048;
static constexpr int NH    = 32;
static constexpr int HD    = 128;
static constexpr int OD    = 4096;    // NH*HD
static constexpr int QKV_O = 12288;   // 3*OD

#define AS1 __attribute__((address_space(1)))
#define AS3 __attribute__((address_space(3)))

typedef __attribute__((ext_vector_type(8))) short bf16x8;
typedef __attribute__((ext_vector_type(4))) float f32x4;
typedef __attribute__((ext_vector_type(4))) short s16x4;

template <int V> struct IC { static constexpr int v = V; };

__device__ __forceinline__ short f2bf(float f) {
  unsigned u = __float_as_uint(f);
  unsigned r = (u + 0x7fffu + ((u >> 16) & 1u)) >> 16;   // RNE
  return (short)r;
}
__device__ __forceinline__ float bf2f(short s) {
  return __uint_as_float(((unsigned)(unsigned short)s) << 16);
}
__device__ __forceinline__ unsigned pk2bf(float a, float b) {
  return __builtin_amdgcn_perm(__float_as_uint(b), __float_as_uint(a), 0x07060302u);
}

// ---------------- fp32 -> bf16 convert: two regions in one launch ----------------
__global__ void convert2_kernel(const float* __restrict__ in1, short* __restrict__ out1, int n1_4,
                                const float* __restrict__ in2, short* __restrict__ out2, int n2_4) {
  int i = blockIdx.x * blockDim.x + threadIdx.x;
  const float* in; short* out; int j;
  if (i < n1_4) { in = in1; out = out1; j = i; }
  else { j = i - n1_4; if (j >= n2_4) return; in = in2; out = out2; }
  float4 f = ((const float4*)in)[j];
  s16x4 s;
  s.x = f2bf(f.x); s.y = f2bf(f.y); s.z = f2bf(f.z); s.w = f2bf(f.w);
  ((s16x4*)out)[j] = s;
}

// ================= generic 128xBNT 4-PHASE bf16 NT GEMM (fat phases) =================
// C[M,N] = A[M,K](bf16) * B[N,K]^T(bf16). 8 waves (2M x 4N), per-wave 64 x BNT/4.
// Cross-round finding (r2/r3/r5): phase wall-time is ~constant (~800 cyc: barrier+lgkm
// sync across 8 waves); util = MFMA-per-phase / const. So: 4 phases/iter, each with
// 2x the MFMA of the old 8-phase (16/wave for BNT=256, 8 for BNT=128), half the barriers.
// Per K-tile: ph_a reads A-half0 + ALL B (4+2*NJ ds_read_b128), ph_b reads A-half1 (4).
// B frags stay live in regs across the two phases.
//
// Staging ledger (tiles t->buf0, t+1->buf1; 2 K-tiles/iter; BH = BNT/128 in {1,2}):
//   ph1: stage A(t+1)->b1   [A-b1 all-waves-dead since prev ph4-ending BAR]
//   ph2: stage B(t+2)->b0   [B-b0 dead since ph1-LGK + ph1-ending BAR]
//   ph3: stage A(t+2)->b0   [A-b0 dead since ph2-LGK + BAR]
//   ph4: stage B(t+3)->b1   [B-b1 dead since ph3-LGK + BAR]
// Loads/thread: ph1:2, ph2:2BH, ph3:2, ph4:2BH.
// Outstanding-count trace (steady, BH=2): at ph2-end: prevB(t+1)4 + A(t+1)2 + B(t+2)4 = 10,
//   need oldest 6 (B(t+1),A(t+1)) landed before ph3 reads -> vmcnt(4).
//   at ph4-end: B(t+2)4 + A(t+2)2 + B(t+3)4 = 10, need oldest 6 -> vmcnt(4).
// BH=1: 6 outstanding, need oldest 4 -> vmcnt(2) at both.
// Prologue: B(0),A(0),B(1) staged; vmcnt(2BH) retires tile0, keeps B(1); first ph1
// stages A(1) (read first-iter ph3, covered by first ph2-end vmcnt). Clamped tail
// restages write identical bytes (benign).
// XCD 2D-chunk mapping kept from r5 (FETCH 400->123 MB). LDS granule swizzle
// g^=(row>>1)&7 via inverse-permuted source (0 conflicts, r2-r5).
template <int BNT, int CMODE>
__global__ __launch_bounds__(512, 2) void gemm4p(
    const short* __restrict__ A, const short* __restrict__ Bw, void* __restrict__ Cp,
    int K, int N, int ldc) {
  constexpr int BH  = BNT / 128;   // 1 or 2
  constexpr int NJ  = BNT / 64;    // per-wave N frags (2 or 4)
  __shared__ short Al[2][128 * 64];        // 32 KB
  __shared__ short Bl[2][BH][128 * 64];    // BH * 32 KB
  const int tid  = threadIdx.x;
  const int lane = tid & 63;
  const int quad = lane >> 4;
  const int col  = lane & 15;
  const int wave = tid >> 6;
  const int wm   = wave >> 2;
  const int wn   = wave & 3;

  // XCD 2D-chunk mapping (requires nbn % 8 == 0)
  const int nbn = N / BNT;
  const int nbm = gridDim.x / nbn;
  const int xcd = blockIdx.x & 7;
  const int u   = blockIdx.x >> 3;
  const int m0  = (u % nbm) * 128;
  const int n0  = (xcd * (nbn >> 3) + u / nbm) * BNT;

  const int NT = K >> 6;

  f32x4 acc[4][NJ] = {};
  bf16x8 a[2][2], b[NJ][2];

  auto stA = [&](int t, int buf) {
#pragma unroll
    for (int r = 0; r < 2; ++r) {
      int idx = r * 512 + tid;
      int row = idx >> 3;
      int g   = idx & 7;
      int gs  = g ^ ((row >> 1) & 7);
      const short* ga = A + (size_t)(m0 + row) * K + t * 64 + gs * 8;
      __builtin_amdgcn_global_load_lds((const AS1 unsigned*)ga,
                                       (AS3 unsigned*)&Al[buf][idx * 8], 16, 0, 0);
    }
  };
  auto stB = [&](int t, int buf) {
#pragma unroll
    for (int h = 0; h < BH; ++h)
#pragma unroll
      for (int r = 0; r < 2; ++r) {
        int idx = r * 512 + tid;
        int row = idx >> 3;
        int g   = idx & 7;
        int gs  = g ^ ((row >> 1) & 7);
        const short* gb = Bw + (size_t)(n0 + h * 128 + row) * K + t * 64 + gs * 8;
        __builtin_amdgcn_global_load_lds((const AS1 unsigned*)gb,
                                         (AS3 unsigned*)&Bl[buf][h][idx * 8], 16, 0, 0);
      }
  };
  auto rdA = [&](int buf, int mh) {
#pragma unroll
    for (int i = 0; i < 2; ++i) {
      int rh = wm * 64 + (mh * 2 + i) * 16 + col;
#pragma unroll
      for (int kf = 0; kf < 2; ++kf)
        a[i][kf] =
            *(const bf16x8*)&Al[buf][rh * 64 + (((kf * 4 + quad) ^ ((rh >> 1) & 7)) * 8)];
    }
  };
  auto rdB = [&](int buf) {
#pragma unroll
    for (int j = 0; j < NJ; ++j) {
      int br = wn * (BNT / 4) + j * 16 + col;
      int bh = br >> 7, rh = br & 127;
#pragma unroll
      for (int kf = 0; kf < 2; ++kf)
        b[j][kf] =
            *(const bf16x8*)&Bl[buf][bh][rh * 64 + (((kf * 4 + quad) ^ ((rh >> 1) & 7)) * 8)];
    }
  };
  auto mm = [&](auto MH) {
    constexpr int mh = MH.v;
    __builtin_amdgcn_s_setprio(1);
#pragma unroll
    for (int i = 0; i < 2; ++i)
#pragma unroll
      for (int j = 0; j < NJ; ++j)
#pragma unroll
        for (int kf = 0; kf < 2; ++kf)
          acc[mh * 2 + i][j] = __builtin_amdgcn_mfma_f32_16x16x32_bf16(
              a[i][kf], b[j][kf], acc[mh * 2 + i][j], 0, 0, 0);
    __builtin_amdgcn_s_setprio(0);
  };
#define LGK() do { asm volatile("s_waitcnt lgkmcnt(0)"); __builtin_amdgcn_sched_barrier(0); } while (0)
#define BAR() __builtin_amdgcn_s_barrier()
  auto vmc = [] {
    if constexpr (BH == 2) asm volatile("s_waitcnt vmcnt(4)" ::: "memory");
    else                   asm volatile("s_waitcnt vmcnt(2)" ::: "memory");
  };

  // prologue: B(0),A(0)->b0, B(1)->b1; retire tile0, keep B(1) in flight
  stB(0, 0);
  stA(0, 0);
  stB(1, 1);
  vmc();
  BAR();

  for (int i = 0; i < (NT >> 1); ++i) {
    const int t  = 2 * i;
    const int tA = (t + 2 < NT) ? t + 2 : NT - 2;   // clamped restage: identical bytes
    const int tB = (t + 3 < NT) ? t + 3 : NT - 1;
    // ph1: tile t, A-half0 + all B
    rdA(0, 0); rdB(0);
    stA(t + 1, 1);
    BAR(); LGK();
    mm(IC<0>{});
    BAR();
    // ph2: tile t, A-half1 (B reused from regs)
    rdA(0, 1);
    stB(tA, 0);
    BAR(); LGK();
    mm(IC<1>{});
    vmc();
    BAR();
    // ph3: tile t+1, A-half0 + all B
    rdA(1, 0); rdB(1);
    stA(tA, 0);
    BAR(); LGK();
    mm(IC<0>{});
    BAR();
    // ph4: tile t+1, A-half1
    rdA(1, 1);
    stB(tB, 1);
    BAR(); LGK();
    mm(IC<1>{});
    vmc();
    BAR();
  }
#undef LGK
#undef BAR

  // epilogue: C/D layout col=lane&15, row=quad*4+reg
#pragma unroll
  for (int mi = 0; mi < 4; ++mi)
#pragma unroll
    for (int nj = 0; nj < NJ; ++nj)
#pragma unroll
      for (int r = 0; r < 4; ++r) {
        int rr = m0 + wm * 64 + mi * 16 + quad * 4 + r;
        int cc = n0 + wn * (BNT / 4) + nj * 16 + col;
        if (CMODE == 1)
          ((float*)Cp)[(size_t)rr * ldc + cc] = acc[mi][nj][r];
        else
          ((short*)Cp)[(size_t)rr * ldc + cc] = f2bf(acc[mi][nj][r]);
      }
}

// ---------------- NT GEMM: A(bf16) * B^T(f32) — fallback path only ----------------
#define BM 128
#define BK 32

template <int BNT, int CMODE>
__global__ __launch_bounds__(256, 2) void gemm_nt_f32w(
    const short* __restrict__ A, const float* __restrict__ B, void* __restrict__ Cp,
    int K, int ldc) {
  __shared__ short Alds[2][BM * BK];
  __shared__ short Blds[2][BNT * BK];
  constexpr int WN  = BNT / 2;
  constexpr int NJ  = WN / 16;
  constexpr int BCH = (BNT * 4) / 256;
  const int tid  = threadIdx.x;
  const int lane = tid & 63;
  const int quad = lane >> 4;
  const int col  = lane & 15;
  const int wave = tid >> 6;
  const int m0 = blockIdx.y * BM;
  const int n0 = blockIdx.x * BNT;
  const int wm = (wave & 1) * 64;
  const int wn = (wave >> 1) * WN;

  f32x4 acc[4][NJ] = {};
  float4 breg[BCH][2];

  const int nk = K / BK;

  auto b_issue = [&](int k0) {
#pragma unroll
    for (int it = 0; it < BCH; ++it) {
      int idx = it * 256 + tid;
      int row = idx >> 2;
      int c   = idx & 3;
      const float* gb = B + (size_t)(n0 + row) * K + k0 + c * 8;
      breg[it][0] = *(const float4*)gb;
      breg[it][1] = *(const float4*)(gb + 4);
    }
  };
  auto a_issue = [&](int k0, int buf) {
#pragma unroll
    for (int it = 0; it < 2; ++it) {
      int idx = it * 256 + tid;
      int row = idx >> 2;
      int c   = idx & 3;
      int cs  = c ^ ((row >> 1) & 3);
      const short* ga = A + (size_t)(m0 + row) * K + k0 + cs * 8;
      __builtin_amdgcn_global_load_lds((const AS1 unsigned*)ga,
                                       (AS3 unsigned*)&Alds[buf][idx * 8], 16, 0, 0);
    }
  };
  auto b_write = [&](int buf) {
#pragma unroll
    for (int it = 0; it < BCH; ++it) {
      int idx = it * 256 + tid;
      int row = idx >> 2;
      int c   = idx & 3;
      int cw  = c ^ ((row >> 1) & 3);
      union { unsigned u[4]; bf16x8 v; } pk;
      pk.u[0] = pk2bf(breg[it][0].x, breg[it][0].y);
      pk.u[1] = pk2bf(breg[it][0].z, breg[it][0].w);
      pk.u[2] = pk2bf(breg[it][1].x, breg[it][1].y);
      pk.u[3] = pk2bf(breg[it][1].z, breg[it][1].w);
      *(bf16x8*)&Blds[buf][(row * 4 + cw) * 8] = pk.v;
    }
  };
  auto compute = [&](int buf) {
    bf16x8 a[4], b[NJ];
#pragma unroll
    for (int i = 0; i < 4; ++i) {
      int row = wm + i * 16 + col;
      a[i] = *(const bf16x8*)&Alds[buf][(row * 4 + (quad ^ ((row >> 1) & 3))) * 8];
    }
#pragma unroll
    for (int j = 0; j < NJ; ++j) {
      int row = wn + j * 16 + col;
      b[j] = *(const bf16x8*)&Blds[buf][(row * 4 + (quad ^ ((row >> 1) & 3))) * 8];
    }
#pragma unroll
    for (int i = 0; i < 4; ++i)
#pragma unroll
      for (int j = 0; j < NJ; ++j)
        acc[i][j] = __builtin_amdgcn_mfma_f32_16x16x32_bf16(a[i], b[j], acc[i][j], 0, 0, 0);
  };

  b_issue(0);
  a_issue(0, 0);
  b_write(0);
  __syncthreads();

  for (int t = 0; t < nk - 1; ++t) {
    const int cur = t & 1;
    b_issue((t + 1) * BK);
    a_issue((t + 1) * BK, cur ^ 1);
    compute(cur);
    b_write(cur ^ 1);
    __syncthreads();
  }
  compute((nk - 1) & 1);

#pragma unroll
  for (int i = 0; i < 4; ++i)
#pragma unroll
    for (int j = 0; j < NJ; ++j)
#pragma unroll
      for (int r = 0; r < 4; ++r) {
        int rr = m0 + wm + i * 16 + quad * 4 + r;
        int cc = n0 + wn + j * 16 + col;
        if (CMODE == 1)
          ((float*)Cp)[(size_t)rr * ldc + cc] = acc[i][j][r];
        else
          ((short*)Cp)[(size_t)rr * ldc + cc] = f2bf(acc[i][j][r]);
      }
}

// ------- fused: RMSNorm+RoPE on q,k (blocks [0,32768)) + V pack (blocks [32768,33792)) ----
__global__ void normrope_packv_kernel(short* __restrict__ qkv,
                                      const int* __restrict__ positions,
                                      const float* __restrict__ qw,
                                      const float* __restrict__ kw,
                                      short* __restrict__ vtp) {
  __shared__ short T[64][136];
  if (blockIdx.x < 32768) {
    int item = blockIdx.x * 4 + (threadIdx.x >> 6);
    int lane = threadIdx.x & 63;
    int head  = item & 31;
    int which = (item >> 5) & 1;
    int s     = item >> 6;
    const float* w = which ? kw : qw;
    short* base = qkv + (size_t)s * QKV_O + which * OD + head * HD;

    float x1 = bf2f(base[lane]);
    float x2 = bf2f(base[lane + 64]);
    float ss = x1 * x1 + x2 * x2;
#pragma unroll
    for (int d = 32; d; d >>= 1) ss += __shfl_xor(ss, d);
    float r = rsqrtf(ss * (1.0f / 128.0f) + 1e-5f);
    float xn1 = x1 * r * w[lane];
    float xn2 = x2 * r * w[lane + 64];

    float pos = (float)positions[s];
    float inv_freq = exp2f((float)lane * (-13.287712379549449f / 64.0f));
    float f = pos * inv_freq;
    float c = cosf(f), sn = sinf(f);
    float sc = which ? 1.0f : 0.12751863738f;   // q: fold scale*log2(e)
    base[lane]      = f2bf((xn1 * c - xn2 * sn) * sc);
    base[lane + 64] = f2bf((xn2 * c + xn1 * sn) * sc);
  } else {
    int bid2 = blockIdx.x - 32768;
    const int h  = bid2 & 31;
    const int kt = bid2 >> 5;
    const int tid = threadIdx.x;
    {
      int rr = tid >> 2;
      int db = (tid & 3) * 32;
      const short* src = qkv + (size_t)(kt * 64 + rr) * QKV_O + 2 * OD + h * HD + db;
#pragma unroll
      for (int i = 0; i < 4; ++i)
        *(bf16x8*)&T[rr][db + i * 8] = *(const bf16x8*)(src + i * 8);
    }
    __syncthreads();
    {
      int d  = tid >> 1;
      int k0 = (tid & 1) * 32;
      short* dst = vtp + (((size_t)h * 32 + kt) * 128 + d) * 64 + k0;
#pragma unroll
      for (int c = 0; c < 4; ++c) {
        bf16x8 v;
#pragma unroll
        for (int j = 0; j < 8; ++j) v[j] = T[k0 + c * 8 + j][d];
        *(bf16x8*)&dst[c * 8] = v;
      }
    }
  }
}

// ---------------- flash attention (causal), Bq=64/Bk=64 paired, dbuf + async-stage ------
// r6: r3's proven dbuf structure (2 blk/CU, loads-before-barrier, writeKV-after-compute)
// + setprio around MFMA clusters (T5) + defer-max THR=8 (T13).
__global__ __launch_bounds__(256, 2) void attn_kernel(
    const short* __restrict__ qkv, const short* __restrict__ vtp, short* __restrict__ obuf) {
  __shared__ short Klds[2][64 * 128];   // 2 x 16 KB
  __shared__ short Vt[2][128 * 64];     // 2 x 16 KB
  __shared__ short Plds[4][16 * 64];    // 8 KB

  const int tid  = threadIdx.x;
  const int lane = tid & 63;
  const int wave = tid >> 6;
  const int quad = lane >> 4;
  const int col  = lane & 15;
  const int h    = blockIdx.y;

  const int kr  = tid >> 2;
  const int kcb = (tid & 3) * 32;
  const int vd  = tid >> 1;
  const int vcb = (tid & 1) * 32;

  bf16x8 kreg[4], vreg[4];

  auto loadK = [&](int kt) {
    const short* kp = qkv + (size_t)(kt * 64 + kr) * QKV_O + OD + h * HD + kcb;
#pragma unroll
    for (int i = 0; i < 4; ++i) kreg[i] = *(const bf16x8*)(kp + i * 8);
  };
  auto loadV = [&](int kt) {
    const short* vp = vtp + (((size_t)h * 32 + kt) * 128 + vd) * 64 + vcb;
#pragma unroll
    for (int i = 0; i < 4; ++i) vreg[i] = *(const bf16x8*)(vp + i * 8);
  };
  auto writeKV = [&](int buf) {
#pragma unroll
    for (int i = 0; i < 4; ++i) {
      int swz = ((tid & 3) * 4 + i) ^ (kr & 15);
      *(bf16x8*)&Klds[buf][kr * 128 + swz * 8] = kreg[i];
    }
#pragma unroll
    for (int i = 0; i < 4; ++i) {
      int swz = ((tid & 1) * 4 + i) ^ (vd & 7);
      *(bf16x8*)&Vt[buf][vd * 64 + swz * 8] = vreg[i];
    }
  };

#pragma unroll 1
  for (int half = 0; half < 2; ++half) {
    const int qt = half == 0 ? blockIdx.x : 31 - blockIdx.x;   // paired: 33 k-iters/block
    const int qbase = qt * 64 + wave * 16;

    bf16x8 qf[4];
#pragma unroll
    for (int kf = 0; kf < 4; ++kf)
      qf[kf] = *(const bf16x8*)(qkv + (size_t)(qbase + col) * QKV_O + h * HD + kf * 32 + quad * 8);

    f32x4 o[8] = {};
    float m_r[4], l_i[4];
#pragma unroll
    for (int r = 0; r < 4; ++r) { m_r[r] = -1e30f; l_i[r] = 0.f; }

    // prologue: stage kt=0 into buf0 (barrier first: prior half may still read LDS)
    loadK(0); loadV(0);
    __syncthreads();
    writeKV(0);

#pragma unroll 1
    for (int kt = 0; kt <= qt; ++kt) {
      const int cur = kt & 1;
      if (kt < qt) { loadK(kt + 1); loadV(kt + 1); }   // T14: issue early
      __syncthreads();                                  // buf[cur] writes visible

      // S = Q K^T
      f32x4 sfr[4];
      __builtin_amdgcn_s_setprio(1);
#pragma unroll
      for (int nf = 0; nf < 4; ++nf) {
        f32x4 acc = {};
#pragma unroll
        for (int kf = 0; kf < 4; ++kf) {
          bf16x8 b = *(const bf16x8*)&Klds[cur][(nf * 16 + col) * 128 + ((kf * 4 + quad) ^ col) * 8];
          acc = __builtin_amdgcn_mfma_f32_16x16x32_bf16(qf[kf], b, acc, 0, 0, 0);
        }
        sfr[nf] = acc;
      }
      __builtin_amdgcn_s_setprio(0);

      if (kt == qt) {   // diagonal: causal mask
#pragma unroll
        for (int nf = 0; nf < 4; ++nf)
#pragma unroll
          for (int r = 0; r < 4; ++r) {
            int key = kt * 64 + nf * 16 + col;
            int qg  = qbase + quad * 4 + r;
            if (key > qg) sfr[nf][r] = -1e30f;
          }
      }

      // online softmax (log2 domain) with defer-max (T13, THR=8, wave-uniform)
#pragma unroll
      for (int r = 0; r < 4; ++r) {
        float mt = fmaxf(fmaxf(sfr[0][r], sfr[1][r]), fmaxf(sfr[2][r], sfr[3][r]));
#pragma unroll
        for (int d = 8; d; d >>= 1) mt = fmaxf(mt, __shfl_xor(mt, d));
        float mnew = fmaxf(m_r[r], mt);
        bool defer = __all(mnew - m_r[r] <= 8.0f);
        if (defer) mnew = m_r[r];
        float alpha = exp2f(m_r[r] - mnew);
        float ps = 0.f;
#pragma unroll
        for (int nf = 0; nf < 4; ++nf) {
          float p = exp2f(sfr[nf][r] - mnew);
          sfr[nf][r] = p;
          ps += p;
        }
        l_i[r] = l_i[r] * alpha + ps;
        if (!defer) {
#pragma unroll
          for (int nf = 0; nf < 8; ++nf) o[nf][r] *= alpha;
          m_r[r] = mnew;
        }
      }

      // P -> per-wave LDS (C-layout scatter -> A-layout rows), swizzled
#pragma unroll
      for (int nf = 0; nf < 4; ++nf)
#pragma unroll
        for (int r = 0; r < 4; ++r) {
          int row = quad * 4 + r;
          int key = nf * 16 + col;
          Plds[wave][row * 64 + ((key >> 3) ^ (row & 7)) * 8 + (key & 7)] = f2bf(sfr[nf][r]);
        }

      // O += P V
      bf16x8 pa[2];
#pragma unroll
      for (int kf = 0; kf < 2; ++kf)
        pa[kf] = *(const bf16x8*)&Plds[wave][col * 64 + ((kf * 4 + quad) ^ (col & 7)) * 8];
      __builtin_amdgcn_s_setprio(1);
#pragma unroll
      for (int nf = 0; nf < 8; ++nf)
#pragma unroll
        for (int kf = 0; kf < 2; ++kf) {
          bf16x8 vb = *(const bf16x8*)&Vt[cur][(nf * 16 + col) * 64 + ((kf * 4 + quad) ^ (col & 7)) * 8];
          o[nf] = __builtin_amdgcn_mfma_f32_16x16x32_bf16(pa[kf], vb, o[nf], 0, 0, 0);
        }
      __builtin_amdgcn_s_setprio(0);

      if (kt < qt) writeKV(cur ^ 1);   // vmcnt for kreg/vreg lands here, after compute
    }

    // epilogue
#pragma unroll
    for (int r = 0; r < 4; ++r) {
      float lt = l_i[r];
#pragma unroll
      for (int d = 8; d; d >>= 1) lt += __shfl_xor(lt, d);
      float inv = 1.0f / lt;
      int sg = qbase + quad * 4 + r;
#pragma unroll
      for (int nf = 0; nf < 8; ++nf)
        obuf[(size_t)sg * OD + h * HD + nf * 16 + col] = f2bf(o[nf][r] * inv);
    }
  }
}

// ---------------- launcher ----------------
extern "C" void kernel_launch(void* const* d_in, const int* in_sizes, int n_in,
                              void* d_out, int out_size, void* d_ws, size_t ws_size,
                              hipStream_t stream) {
  (void)in_sizes; (void)n_in; (void)out_size;
  const float* hs   = (const float*)d_in[0];
  const int*   pos  = (const int*)d_in[1];
  const float* qkvw = (const float*)d_in[2];
  const float* qw   = (const float*)d_in[3];
  const float* kw   = (const float*)d_in[4];
  const float* ow   = (const float*)d_in[5];
  float* out = (float*)d_out;

  // ws plan: [0,48M) qkvb | [48M,64M) obuf | [64M,112M) qkvw_bf, later ow_bf (fast path)
  char* ws = (char*)d_ws;
  short* qkvb    = (short*)(ws);
  short* obuf    = (short*)(ws + 50331648);
  short* qkvw_bf = (short*)(ws + 67108864);
  short* ow_bf   = (short*)(ws + 67108864);   // reuses qkvw_bf region after GEMM1
  short* hsb  = (short*)d_out;
  short* vtp  = (short*)d_out;

  const bool fast = ws_size >= (size_t)117440512;

  if (fast) {
    // 1) convert hidden_states AND qkv_w -> bf16 in one launch
    int n1 = (S_LEN * HID) / 4, n2 = (QKV_O * HID) / 4;
    convert2_kernel<<<(n1 + n2 + 255) / 256, 256, 0, stream>>>(hs, hsb, n1, qkvw, qkvw_bf, n2);
    // 2) qkv = hs @ qkv_w^T : 128x256 tiles -> 768 blocks (3 balanced rounds), 4-phase
    gemm4p<256, 0><<<(S_LEN / 128) * (QKV_O / 256), 512, 0, stream>>>(
        hsb, qkvw_bf, qkvb, HID, QKV_O, QKV_O);
    // 2b) convert o_proj_w -> bf16 into the now-dead qkvw_bf region
    int n3 = (HID * OD) / 4;
    convert2_kernel<<<(n3 + 255) / 256, 256, 0, stream>>>(ow, ow_bf, n3, ow, ow_bf, 0);
  } else {
    int n1 = (S_LEN * HID) / 4;
    convert2_kernel<<<(n1 + 255) / 256, 256, 0, stream>>>(hs, hsb, n1, hs, hsb, 0);
    gemm_nt_f32w<128, 0><<<dim3(QKV_O / 128, S_LEN / BM), 256, 0, stream>>>(
        hsb, qkvw, qkvb, HID, QKV_O);
  }

  // 3+4) RMSNorm+RoPE on q,k AND V pack, one launch
  normrope_packv_kernel<<<(S_LEN * 2 * NH) / 4 + NH * (S_LEN / 64), 256, 0, stream>>>(
      qkvb, pos, qw, kw, vtp);

  // 5) causal flash attention -> obuf
  attn_kernel<<<dim3(16, NH), 256, 0, stream>>>(qkvb, vtp, obuf);

  // 6) out = obuf @ o_proj_w^T (fp32 C)
  if (fast) {
    // 128x128 tiles -> 256 blocks = 1 exact CU round, K=4096, 4-phase
    gemm4p<128, 1><<<(S_LEN / 128) * (HID / 128), 512, 0, stream>>>(
        obuf, ow_bf, out, OD, HID, HID);
  } else {
    gemm_nt_f32w<64, 1><<<dim3(HID / 64, S_LEN / BM), 256, 0, stream>>>(
        obuf, ow, out, OD, HID);
  }
}

// Round 8
// 480.207 us; speedup vs baseline: 1.0228x; 1.0228x over previous
//
#include <hip/hip_runtime.h>
#include <cstdint>
#include <cstddef>

// ---- problem constants ----
static constexpr int S_LEN = 2048;
static constexpr int HID   = 2048;
static constexpr int NH    = 32;
static constexpr int HD    = 128;
static constexpr int OD    = 4096;    // NH*HD
static constexpr int QKV_O = 12288;   // 3*OD

#define AS1 __attribute__((address_space(1)))
#define AS3 __attribute__((address_space(3)))

typedef __attribute__((ext_vector_type(8))) short bf16x8;
typedef __attribute__((ext_vector_type(4))) float f32x4;
typedef __attribute__((ext_vector_type(4))) short s16x4;

template <int V> struct IC { static constexpr int v = V; };

__device__ __forceinline__ short f2bf(float f) {
  unsigned u = __float_as_uint(f);
  unsigned r = (u + 0x7fffu + ((u >> 16) & 1u)) >> 16;   // RNE
  return (short)r;
}
__device__ __forceinline__ float bf2f(short s) {
  return __uint_as_float(((unsigned)(unsigned short)s) << 16);
}
__device__ __forceinline__ unsigned pk2bf(float a, float b) {
  return __builtin_amdgcn_perm(__float_as_uint(b), __float_as_uint(a), 0x07060302u);
}

// ---------------- fp32 -> bf16 convert: two regions in one launch ----------------
__global__ void convert2_kernel(const float* __restrict__ in1, short* __restrict__ out1, int n1_4,
                                const float* __restrict__ in2, short* __restrict__ out2, int n2_4) {
  int i = blockIdx.x * blockDim.x + threadIdx.x;
  const float* in; short* out; int j;
  if (i < n1_4) { in = in1; out = out1; j = i; }
  else { j = i - n1_4; if (j >= n2_4) return; in = in2; out = out2; }
  float4 f = ((const float4*)in)[j];
  s16x4 s;
  s.x = f2bf(f.x); s.y = f2bf(f.y); s.z = f2bf(f.z); s.w = f2bf(f.w);
  ((s16x4*)out)[j] = s;
}

// ========= generic BMt x BNT 8-phase bf16 NT GEMM (r5's PROVEN sync skeleton) =========
// C[M,N] = A[M,K](bf16) * B[N,K]^T(bf16). 8 waves (2M x 4N), wave tile (BMt/2) x (BNT/4).
// r8: BMt=256 for GEMM1 -- LDS-BW model (r2/r5/r6 invariant: ~660 out*K/cyc/block at
// 0.69 KB LDS traffic per MFMA, ~56 B/cyc/CU) says the lever is bytes/MFMA: wave tile
// 128x64 cuts it to 0.5 (reads 192KB + writes 64KB per K-tile for 512 block-MFMA).
// Sync skeleton is byte-for-byte r5's gemm8p (phases, BAR/LGK placement, vmc positions);
// only counts scale. Loads per K-tile L = 2*(BMt/128) + 2*BH:
//   BMt=256,BH=2: L=8 | BMt=128,BH=2: L=6 (r5-proven) | BMt=128,BH=1: L=4 (r5-proven).
// Outstanding trace (steady): entering ph1: L (odd-tile stages). ph3/ph4 stage tile t+2
// (+L) -> ph4-end vmcnt(L) drains the odd tile (oldest L) before ph5 reads, then BAR ->
// cross-wave certified (each wave waits its own counter BEFORE the barrier -- the r7 bug
// was violating exactly this). ph7/ph8 stage tile t+3 (+L) -> ph8-end vmcnt(L) drains
// tile t+2 before next ph1. Prologue stages tiles 0,1 (2L) -> vmcnt(L) retires tile 0.
// Write-after-read: every stage is issued >=1 BAR after the lgkmcnt(0) that retired its
// region's last ds_read on all waves (ph3:B-buf0 dead since ph2; ph4:A-buf0 since ph3;
// ph7:B-buf1 since ph6; ph8:A-buf1 since ph7). Clamped tail restages: identical bytes.
// XCD 2D-chunk mapping (r5, FETCH 400->123MB). Granule swizzle g^=(row>>1)&7 via
// inverse-permuted global source (0 bank conflicts, r2-r6).
template <int BMt, int BNT, int CMODE>
__global__ __launch_bounds__(512, 2) void gemm8p(
    const short* __restrict__ A, const short* __restrict__ Bw, void* __restrict__ Cp,
    int K, int N, int ldc) {
  constexpr int BH  = BNT / 128;   // B half-tiles (1 or 2)
  constexpr int NJ  = BNT / 64;    // per-wave N frags (2 or 4)
  constexpr int NJH = NJ / 2;      // N frags per quadrant
  constexpr int MF  = BMt / 64;    // per-wave M frags per half (2 or 4)
  constexpr int AST = BMt / 64;    // stA sweeps (2 or 4)
  constexpr int LT  = 2 * (BMt / 128) + 2 * BH;   // loads per K-tile
  __shared__ short Al[2][BMt * 64];
  __shared__ short Bl[2][BH][128 * 64];
  const int tid  = threadIdx.x;
  const int lane = tid & 63;
  const int quad = lane >> 4;
  const int col  = lane & 15;
  const int wave = tid >> 6;
  const int wm   = wave >> 2;
  const int wn   = wave & 3;

  // XCD 2D-chunk mapping (requires nbn % 8 == 0)
  const int nbn = N / BNT;
  const int nbm = gridDim.x / nbn;
  const int xcd = blockIdx.x & 7;
  const int u   = blockIdx.x >> 3;
  const int m0  = (u % nbm) * BMt;
  const int n0  = (xcd * (nbn >> 3) + u / nbm) * BNT;

  const int NT = K >> 6;

  f32x4 acc[2 * MF][NJ] = {};
  bf16x8 a[MF][2], b0[NJH][2], b1[NJH][2];

  auto stA = [&](int t, int buf) {
#pragma unroll
    for (int r = 0; r < AST; ++r) {
      int idx = r * 512 + tid;
      int row = idx >> 3;
      int g   = idx & 7;
      int gs  = g ^ ((row >> 1) & 7);
      const short* ga = A + (size_t)(m0 + row) * K + t * 64 + gs * 8;
      __builtin_amdgcn_global_load_lds((const AS1 unsigned*)ga,
                                       (AS3 unsigned*)&Al[buf][idx * 8], 16, 0, 0);
    }
  };
  auto stB = [&](int t, int buf, int h) {
#pragma unroll
    for (int r = 0; r < 2; ++r) {
      int idx = r * 512 + tid;
      int row = idx >> 3;
      int g   = idx & 7;
      int gs  = g ^ ((row >> 1) & 7);
      const short* gb = Bw + (size_t)(n0 + h * 128 + row) * K + t * 64 + gs * 8;
      __builtin_amdgcn_global_load_lds((const AS1 unsigned*)gb,
                                       (AS3 unsigned*)&Bl[buf][h][idx * 8], 16, 0, 0);
    }
  };
  auto rdA = [&](int buf, int mh) {
#pragma unroll
    for (int i = 0; i < MF; ++i) {
      int rh = wm * (BMt / 2) + (mh * MF + i) * 16 + col;
#pragma unroll
      for (int kf = 0; kf < 2; ++kf)
        a[i][kf] =
            *(const bf16x8*)&Al[buf][rh * 64 + (((kf * 4 + quad) ^ ((rh >> 1) & 7)) * 8)];
    }
  };
  auto rdB = [&](int buf, int nh, bf16x8 (&bb)[NJH][2]) {
#pragma unroll
    for (int j = 0; j < NJH; ++j) {
      int br = wn * (BNT / 4) + nh * (BNT / 8) + j * 16 + col;
      int bh = br >> 7, rh = br & 127;
#pragma unroll
      for (int kf = 0; kf < 2; ++kf)
        bb[j][kf] =
            *(const bf16x8*)&Bl[buf][bh][rh * 64 + (((kf * 4 + quad) ^ ((rh >> 1) & 7)) * 8)];
    }
  };
  auto mm = [&](auto MH, auto NHc, bf16x8 (&bb)[NJH][2]) {
    constexpr int mh = MH.v, nh = NHc.v;
    __builtin_amdgcn_s_setprio(1);
#pragma unroll
    for (int i = 0; i < MF; ++i)
#pragma unroll
      for (int j = 0; j < NJH; ++j)
#pragma unroll
        for (int kf = 0; kf < 2; ++kf)
          acc[mh * MF + i][nh * NJH + j] = __builtin_amdgcn_mfma_f32_16x16x32_bf16(
              a[i][kf], bb[j][kf], acc[mh * MF + i][nh * NJH + j], 0, 0, 0);
    __builtin_amdgcn_s_setprio(0);
  };
#define LGK() do { asm volatile("s_waitcnt lgkmcnt(0)"); __builtin_amdgcn_sched_barrier(0); } while (0)
#define BAR() __builtin_amdgcn_s_barrier()
  auto vmc = [] {
    if constexpr (LT == 8)      asm volatile("s_waitcnt vmcnt(8)" ::: "memory");
    else if constexpr (LT == 6) asm volatile("s_waitcnt vmcnt(6)" ::: "memory");
    else                        asm volatile("s_waitcnt vmcnt(4)" ::: "memory");
  };

  // prologue: stage tile0 -> buf0, tile1 -> buf1; retire tile0, keep tile1 in flight
#pragma unroll
  for (int h = 0; h < BH; ++h) stB(0, 0, h);
  stA(0, 0);
#pragma unroll
  for (int h = 0; h < BH; ++h) stB(1, 1, h);
  stA(1, 1);
  vmc();
  BAR();

  for (int i = 0; i < (NT >> 1); ++i) {
    const int t  = 2 * i;
    const int tA = (t + 2 < NT) ? t + 2 : NT - 2;   // clamped restage: identical bytes
    const int tB = (t + 3 < NT) ? t + 3 : NT - 1;
    // ph1
    rdA(0, 0); rdB(0, 0, b0);
    BAR(); LGK();
    mm(IC<0>{}, IC<0>{}, b0);
    BAR();
    // ph2
    rdB(0, 1, b1);
    BAR(); LGK();
    mm(IC<0>{}, IC<1>{}, b1);
    BAR();
    // ph3  (B-buf0 dead since ph2-LGK)
    rdA(0, 1);
    stB(tA, 0, 0);
    BAR(); LGK();
    mm(IC<1>{}, IC<1>{}, b1);
    BAR();
    // ph4  (A-buf0 dead since ph3-LGK)
    if constexpr (BH >= 2) stB(tA, 0, 1);
    stA(tA, 0);
    BAR();
    mm(IC<1>{}, IC<0>{}, b0);
    vmc();
    BAR();
    // ph5
    rdA(1, 0); rdB(1, 0, b0);
    BAR(); LGK();
    mm(IC<0>{}, IC<0>{}, b0);
    BAR();
    // ph6
    rdB(1, 1, b1);
    BAR(); LGK();
    mm(IC<0>{}, IC<1>{}, b1);
    BAR();
    // ph7  (B-buf1 dead since ph6-LGK)
    rdA(1, 1);
    stB(tB, 1, 0);
    if constexpr (BH >= 2) stB(tB, 1, 1);
    BAR(); LGK();
    mm(IC<1>{}, IC<1>{}, b1);
    BAR();
    // ph8  (A-buf1 dead since ph7-LGK)
    stA(tB, 1);
    BAR();
    mm(IC<1>{}, IC<0>{}, b0);
    vmc();
    BAR();
  }
#undef LGK
#undef BAR

  // epilogue: C/D layout col=lane&15, row=quad*4+reg
#pragma unroll
  for (int mi = 0; mi < 2 * MF; ++mi)
#pragma unroll
    for (int nj = 0; nj < NJ; ++nj)
#pragma unroll
      for (int r = 0; r < 4; ++r) {
        int rr = m0 + wm * (BMt / 2) + mi * 16 + quad * 4 + r;
        int cc = n0 + wn * (BNT / 4) + nj * 16 + col;
        if (CMODE == 1)
          ((float*)Cp)[(size_t)rr * ldc + cc] = acc[mi][nj][r];
        else
          ((short*)Cp)[(size_t)rr * ldc + cc] = f2bf(acc[mi][nj][r]);
      }
}

// ---------------- NT GEMM: A(bf16) * B^T(f32) — fallback path only ----------------
#define BM 128
#define BK 32

template <int BNT, int CMODE>
__global__ __launch_bounds__(256, 2) void gemm_nt_f32w(
    const short* __restrict__ A, const float* __restrict__ B, void* __restrict__ Cp,
    int K, int ldc) {
  __shared__ short Alds[2][BM * BK];
  __shared__ short Blds[2][BNT * BK];
  constexpr int WN  = BNT / 2;
  constexpr int NJ  = WN / 16;
  constexpr int BCH = (BNT * 4) / 256;
  const int tid  = threadIdx.x;
  const int lane = tid & 63;
  const int quad = lane >> 4;
  const int col  = lane & 15;
  const int wave = tid >> 6;
  const int m0 = blockIdx.y * BM;
  const int n0 = blockIdx.x * BNT;
  const int wm = (wave & 1) * 64;
  const int wn = (wave >> 1) * WN;

  f32x4 acc[4][NJ] = {};
  float4 breg[BCH][2];

  const int nk = K / BK;

  auto b_issue = [&](int k0) {
#pragma unroll
    for (int it = 0; it < BCH; ++it) {
      int idx = it * 256 + tid;
      int row = idx >> 2;
      int c   = idx & 3;
      const float* gb = B + (size_t)(n0 + row) * K + k0 + c * 8;
      breg[it][0] = *(const float4*)gb;
      breg[it][1] = *(const float4*)(gb + 4);
    }
  };
  auto a_issue = [&](int k0, int buf) {
#pragma unroll
    for (int it = 0; it < 2; ++it) {
      int idx = it * 256 + tid;
      int row = idx >> 2;
      int c   = idx & 3;
      int cs  = c ^ ((row >> 1) & 3);
      const short* ga = A + (size_t)(m0 + row) * K + k0 + cs * 8;
      __builtin_amdgcn_global_load_lds((const AS1 unsigned*)ga,
                                       (AS3 unsigned*)&Alds[buf][idx * 8], 16, 0, 0);
    }
  };
  auto b_write = [&](int buf) {
#pragma unroll
    for (int it = 0; it < BCH; ++it) {
      int idx = it * 256 + tid;
      int row = idx >> 2;
      int c   = idx & 3;
      int cw  = c ^ ((row >> 1) & 3);
      union { unsigned u[4]; bf16x8 v; } pk;
      pk.u[0] = pk2bf(breg[it][0].x, breg[it][0].y);
      pk.u[1] = pk2bf(breg[it][0].z, breg[it][0].w);
      pk.u[2] = pk2bf(breg[it][1].x, breg[it][1].y);
      pk.u[3] = pk2bf(breg[it][1].z, breg[it][1].w);
      *(bf16x8*)&Blds[buf][(row * 4 + cw) * 8] = pk.v;
    }
  };
  auto compute = [&](int buf) {
    bf16x8 a[4], b[NJ];
#pragma unroll
    for (int i = 0; i < 4; ++i) {
      int row = wm + i * 16 + col;
      a[i] = *(const bf16x8*)&Alds[buf][(row * 4 + (quad ^ ((row >> 1) & 3))) * 8];
    }
#pragma unroll
    for (int j = 0; j < NJ; ++j) {
      int row = wn + j * 16 + col;
      b[j] = *(const bf16x8*)&Blds[buf][(row * 4 + (quad ^ ((row >> 1) & 3))) * 8];
    }
#pragma unroll
    for (int i = 0; i < 4; ++i)
#pragma unroll
      for (int j = 0; j < NJ; ++j)
        acc[i][j] = __builtin_amdgcn_mfma_f32_16x16x32_bf16(a[i], b[j], acc[i][j], 0, 0, 0);
  };

  b_issue(0);
  a_issue(0, 0);
  b_write(0);
  __syncthreads();

  for (int t = 0; t < nk - 1; ++t) {
    const int cur = t & 1;
    b_issue((t + 1) * BK);
    a_issue((t + 1) * BK, cur ^ 1);
    compute(cur);
    b_write(cur ^ 1);
    __syncthreads();
  }
  compute((nk - 1) & 1);

#pragma unroll
  for (int i = 0; i < 4; ++i)
#pragma unroll
    for (int j = 0; j < NJ; ++j)
#pragma unroll
      for (int r = 0; r < 4; ++r) {
        int rr = m0 + wm + i * 16 + quad * 4 + r;
        int cc = n0 + wn + j * 16 + col;
        if (CMODE == 1)
          ((float*)Cp)[(size_t)rr * ldc + cc] = acc[i][j][r];
        else
          ((short*)Cp)[(size_t)rr * ldc + cc] = f2bf(acc[i][j][r]);
      }
}

// --- fused: RMSNorm+RoPE q,k [0,32768) + V pack [32768,33792) + o_proj convert [33792,...) ---
__global__ void normrope_packv_kernel(short* __restrict__ qkv,
                                      const int* __restrict__ positions,
                                      const float* __restrict__ qw,
                                      const float* __restrict__ kw,
                                      short* __restrict__ vtp,
                                      const float* __restrict__ ow,
                                      short* __restrict__ ow_bf,
                                      int n3_4) {
  __shared__ short T[64][136];
  if (blockIdx.x < 32768) {
    int item = blockIdx.x * 4 + (threadIdx.x >> 6);
    int lane = threadIdx.x & 63;
    int head  = item & 31;
    int which = (item >> 5) & 1;
    int s     = item >> 6;
    const float* w = which ? kw : qw;
    short* base = qkv + (size_t)s * QKV_O + which * OD + head * HD;

    float x1 = bf2f(base[lane]);
    float x2 = bf2f(base[lane + 64]);
    float ss = x1 * x1 + x2 * x2;
#pragma unroll
    for (int d = 32; d; d >>= 1) ss += __shfl_xor(ss, d);
    float r = rsqrtf(ss * (1.0f / 128.0f) + 1e-5f);
    float xn1 = x1 * r * w[lane];
    float xn2 = x2 * r * w[lane + 64];

    float pos = (float)positions[s];
    float inv_freq = exp2f((float)lane * (-13.287712379549449f / 64.0f));
    float f = pos * inv_freq;
    float c = cosf(f), sn = sinf(f);
    float sc = which ? 1.0f : 0.12751863738f;   // q: fold scale*log2(e)
    base[lane]      = f2bf((xn1 * c - xn2 * sn) * sc);
    base[lane + 64] = f2bf((xn2 * c + xn1 * sn) * sc);
  } else if (blockIdx.x < 33792) {
    int bid2 = blockIdx.x - 32768;
    const int h  = bid2 & 31;
    const int kt = bid2 >> 5;
    const int tid = threadIdx.x;
    {
      int rr = tid >> 2;
      int db = (tid & 3) * 32;
      const short* src = qkv + (size_t)(kt * 64 + rr) * QKV_O + 2 * OD + h * HD + db;
#pragma unroll
      for (int i = 0; i < 4; ++i)
        *(bf16x8*)&T[rr][db + i * 8] = *(const bf16x8*)(src + i * 8);
    }
    __syncthreads();
    {
      int d  = tid >> 1;
      int k0 = (tid & 1) * 32;
      short* dst = vtp + (((size_t)h * 32 + kt) * 128 + d) * 64 + k0;
#pragma unroll
      for (int c = 0; c < 4; ++c) {
        bf16x8 v;
#pragma unroll
        for (int j = 0; j < 8; ++j) v[j] = T[k0 + c * 8 + j][d];
        *(bf16x8*)&dst[c * 8] = v;
      }
    }
  } else {
    int i = (blockIdx.x - 33792) * 256 + threadIdx.x;
    if (i >= n3_4) return;
    float4 f = ((const float4*)ow)[i];
    s16x4 s;
    s.x = f2bf(f.x); s.y = f2bf(f.y); s.z = f2bf(f.z); s.w = f2bf(f.w);
    ((s16x4*)ow_bf)[i] = s;
  }
}

// ---------------- flash attention (causal), Bq=64/Bk=64 paired, dbuf + async-stage ------
// r6 exact (proven): dbuf, loads-before-barrier, writeKV-after-compute, T5 setprio,
// T13 defer-max THR=8.
__global__ __launch_bounds__(256, 2) void attn_kernel(
    const short* __restrict__ qkv, const short* __restrict__ vtp, short* __restrict__ obuf) {
  __shared__ short Klds[2][64 * 128];   // 2 x 16 KB
  __shared__ short Vt[2][128 * 64];     // 2 x 16 KB
  __shared__ short Plds[4][16 * 64];    // 8 KB

  const int tid  = threadIdx.x;
  const int lane = tid & 63;
  const int wave = tid >> 6;
  const int quad = lane >> 4;
  const int col  = lane & 15;
  const int h    = blockIdx.y;

  const int kr  = tid >> 2;
  const int kcb = (tid & 3) * 32;
  const int vd  = tid >> 1;
  const int vcb = (tid & 1) * 32;

  bf16x8 kreg[4], vreg[4];

  auto loadK = [&](int kt) {
    const short* kp = qkv + (size_t)(kt * 64 + kr) * QKV_O + OD + h * HD + kcb;
#pragma unroll
    for (int i = 0; i < 4; ++i) kreg[i] = *(const bf16x8*)(kp + i * 8);
  };
  auto loadV = [&](int kt) {
    const short* vp = vtp + (((size_t)h * 32 + kt) * 128 + vd) * 64 + vcb;
#pragma unroll
    for (int i = 0; i < 4; ++i) vreg[i] = *(const bf16x8*)(vp + i * 8);
  };
  auto writeKV = [&](int buf) {
#pragma unroll
    for (int i = 0; i < 4; ++i) {
      int swz = ((tid & 3) * 4 + i) ^ (kr & 15);
      *(bf16x8*)&Klds[buf][kr * 128 + swz * 8] = kreg[i];
    }
#pragma unroll
    for (int i = 0; i < 4; ++i) {
      int swz = ((tid & 1) * 4 + i) ^ (vd & 7);
      *(bf16x8*)&Vt[buf][vd * 64 + swz * 8] = vreg[i];
    }
  };

#pragma unroll 1
  for (int half = 0; half < 2; ++half) {
    const int qt = half == 0 ? blockIdx.x : 31 - blockIdx.x;   // paired: 33 k-iters/block
    const int qbase = qt * 64 + wave * 16;

    bf16x8 qf[4];
#pragma unroll
    for (int kf = 0; kf < 4; ++kf)
      qf[kf] = *(const bf16x8*)(qkv + (size_t)(qbase + col) * QKV_O + h * HD + kf * 32 + quad * 8);

    f32x4 o[8] = {};
    float m_r[4], l_i[4];
#pragma unroll
    for (int r = 0; r < 4; ++r) { m_r[r] = -1e30f; l_i[r] = 0.f; }

    loadK(0); loadV(0);
    __syncthreads();
    writeKV(0);

#pragma unroll 1
    for (int kt = 0; kt <= qt; ++kt) {
      const int cur = kt & 1;
      if (kt < qt) { loadK(kt + 1); loadV(kt + 1); }   // T14: issue early
      __syncthreads();                                  // buf[cur] writes visible

      f32x4 sfr[4];
      __builtin_amdgcn_s_setprio(1);
#pragma unroll
      for (int nf = 0; nf < 4; ++nf) {
        f32x4 acc = {};
#pragma unroll
        for (int kf = 0; kf < 4; ++kf) {
          bf16x8 b = *(const bf16x8*)&Klds[cur][(nf * 16 + col) * 128 + ((kf * 4 + quad) ^ col) * 8];
          acc = __builtin_amdgcn_mfma_f32_16x16x32_bf16(qf[kf], b, acc, 0, 0, 0);
        }
        sfr[nf] = acc;
      }
      __builtin_amdgcn_s_setprio(0);

      if (kt == qt) {
#pragma unroll
        for (int nf = 0; nf < 4; ++nf)
#pragma unroll
          for (int r = 0; r < 4; ++r) {
            int key = kt * 64 + nf * 16 + col;
            int qg  = qbase + quad * 4 + r;
            if (key > qg) sfr[nf][r] = -1e30f;
          }
      }

#pragma unroll
      for (int r = 0; r < 4; ++r) {
        float mt = fmaxf(fmaxf(sfr[0][r], sfr[1][r]), fmaxf(sfr[2][r], sfr[3][r]));
#pragma unroll
        for (int d = 8; d; d >>= 1) mt = fmaxf(mt, __shfl_xor(mt, d));
        float mnew = fmaxf(m_r[r], mt);
        bool defer = __all(mnew - m_r[r] <= 8.0f);
        if (defer) mnew = m_r[r];
        float alpha = exp2f(m_r[r] - mnew);
        float ps = 0.f;
#pragma unroll
        for (int nf = 0; nf < 4; ++nf) {
          float p = exp2f(sfr[nf][r] - mnew);
          sfr[nf][r] = p;
          ps += p;
        }
        l_i[r] = l_i[r] * alpha + ps;
        if (!defer) {
#pragma unroll
          for (int nf = 0; nf < 8; ++nf) o[nf][r] *= alpha;
          m_r[r] = mnew;
        }
      }

#pragma unroll
      for (int nf = 0; nf < 4; ++nf)
#pragma unroll
        for (int r = 0; r < 4; ++r) {
          int row = quad * 4 + r;
          int key = nf * 16 + col;
          Plds[wave][row * 64 + ((key >> 3) ^ (row & 7)) * 8 + (key & 7)] = f2bf(sfr[nf][r]);
        }

      bf16x8 pa[2];
#pragma unroll
      for (int kf = 0; kf < 2; ++kf)
        pa[kf] = *(const bf16x8*)&Plds[wave][col * 64 + ((kf * 4 + quad) ^ (col & 7)) * 8];
      __builtin_amdgcn_s_setprio(1);
#pragma unroll
      for (int nf = 0; nf < 8; ++nf)
#pragma unroll
        for (int kf = 0; kf < 2; ++kf) {
          bf16x8 vb = *(const bf16x8*)&Vt[cur][(nf * 16 + col) * 64 + ((kf * 4 + quad) ^ (col & 7)) * 8];
          o[nf] = __builtin_amdgcn_mfma_f32_16x16x32_bf16(pa[kf], vb, o[nf], 0, 0, 0);
        }
      __builtin_amdgcn_s_setprio(0);

      if (kt < qt) writeKV(cur ^ 1);
    }

#pragma unroll
    for (int r = 0; r < 4; ++r) {
      float lt = l_i[r];
#pragma unroll
      for (int d = 8; d; d >>= 1) lt += __shfl_xor(lt, d);
      float inv = 1.0f / lt;
      int sg = qbase + quad * 4 + r;
#pragma unroll
      for (int nf = 0; nf < 8; ++nf)
        obuf[(size_t)sg * OD + h * HD + nf * 16 + col] = f2bf(o[nf][r] * inv);
    }
  }
}

// ---------------- launcher ----------------
extern "C" void kernel_launch(void* const* d_in, const int* in_sizes, int n_in,
                              void* d_out, int out_size, void* d_ws, size_t ws_size,
                              hipStream_t stream) {
  (void)in_sizes; (void)n_in; (void)out_size;
  const float* hs   = (const float*)d_in[0];
  const int*   pos  = (const int*)d_in[1];
  const float* qkvw = (const float*)d_in[2];
  const float* qw   = (const float*)d_in[3];
  const float* kw   = (const float*)d_in[4];
  const float* ow   = (const float*)d_in[5];
  float* out = (float*)d_out;

  // ws plan: [0,48M) qkvb | [48M,64M) obuf | [64M,112M) qkvw_bf, later ow_bf (fast path)
  char* ws = (char*)d_ws;
  short* qkvb    = (short*)(ws);
  short* obuf    = (short*)(ws + 50331648);
  short* qkvw_bf = (short*)(ws + 67108864);
  short* ow_bf   = (short*)(ws + 67108864);   // reuses qkvw_bf region after GEMM1
  short* hsb  = (short*)d_out;
  short* vtp  = (short*)d_out;

  const bool fast = ws_size >= (size_t)117440512;

  if (fast) {
    // 1) convert hidden_states AND qkv_w -> bf16 in one launch
    int n1 = (S_LEN * HID) / 4, n2 = (QKV_O * HID) / 4;
    convert2_kernel<<<(n1 + n2 + 255) / 256, 256, 0, stream>>>(hs, hsb, n1, qkvw, qkvw_bf, n2);
    // 2) qkv = hs @ qkv_w^T : 256x256 tiles -> 8*48 = 384 blocks, wave tile 128x64
    gemm8p<256, 256, 0><<<(S_LEN / 256) * (QKV_O / 256), 512, 0, stream>>>(
        hsb, qkvw_bf, qkvb, HID, QKV_O, QKV_O);
    // 3+4+2b) RMSNorm+RoPE, V pack, AND o_proj convert (into now-dead qkvw_bf), one launch
    int n3 = (HID * OD) / 4;
    normrope_packv_kernel<<<(S_LEN * 2 * NH) / 4 + NH * (S_LEN / 64) + n3 / 256,
                            256, 0, stream>>>(qkvb, pos, qw, kw, vtp, ow, ow_bf, n3);
  } else {
    int n1 = (S_LEN * HID) / 4;
    convert2_kernel<<<(n1 + 255) / 256, 256, 0, stream>>>(hs, hsb, n1, hs, hsb, 0);
    gemm_nt_f32w<128, 0><<<dim3(QKV_O / 128, S_LEN / BM), 256, 0, stream>>>(
        hsb, qkvw, qkvb, HID, QKV_O);
    normrope_packv_kernel<<<(S_LEN * 2 * NH) / 4 + NH * (S_LEN / 64),
                            256, 0, stream>>>(qkvb, pos, qw, kw, vtp, hs, (short*)d_ws, 0);
  }

  // 5) causal flash attention -> obuf
  attn_kernel<<<dim3(16, NH), 256, 0, stream>>>(qkvb, vtp, obuf);

  // 6) out = obuf @ o_proj_w^T (fp32 C)
  if (fast) {
    // 128x128 tiles -> 256 blocks = 1 exact CU round, K=4096 (r5-proven config)
    gemm8p<128, 128, 1><<<(S_LEN / 128) * (HID / 128), 512, 0, stream>>>(
        obuf, ow_bf, out, OD, HID, HID);
  } else {
    gemm_nt_f32w<64, 1><<<dim3(HID / 64, S_LEN / BM), 256, 0, stream>>>(
        obuf, ow, out, OD, HID);
  }
}

// Round 9
// 475.135 us; speedup vs baseline: 1.0338x; 1.0107x over previous
//
#include <hip/hip_runtime.h>
#include <cstdint>
#include <cstddef>

// ---- problem constants ----
static constexpr int S_LEN = 2048;
static constexpr int HID   = 2048;
static constexpr int NH    = 32;
static constexpr int HD    = 128;
static constexpr int OD    = 4096;    // NH*HD
static constexpr int QKV_O = 12288;   // 3*OD

#define AS1 __attribute__((address_space(1)))
#define AS3 __attribute__((address_space(3)))

typedef __attribute__((ext_vector_type(8))) short bf16x8;
typedef __attribute__((ext_vector_type(4))) float f32x4;
typedef __attribute__((ext_vector_type(4))) short s16x4;

template <int V> struct IC { static constexpr int v = V; };

__device__ __forceinline__ short f2bf(float f) {
  unsigned u = __float_as_uint(f);
  unsigned r = (u + 0x7fffu + ((u >> 16) & 1u)) >> 16;   // RNE
  return (short)r;
}
__device__ __forceinline__ float bf2f(short s) {
  return __uint_as_float(((unsigned)(unsigned short)s) << 16);
}
__device__ __forceinline__ unsigned pk2bf(float a, float b) {
  return __builtin_amdgcn_perm(__float_as_uint(b), __float_as_uint(a), 0x07060302u);
}

// ---------------- fp32 -> bf16 convert: two regions in one launch ----------------
__global__ void convert2_kernel(const float* __restrict__ in1, short* __restrict__ out1, int n1_4,
                                const float* __restrict__ in2, short* __restrict__ out2, int n2_4) {
  int i = blockIdx.x * blockDim.x + threadIdx.x;
  const float* in; short* out; int j;
  if (i < n1_4) { in = in1; out = out1; j = i; }
  else { j = i - n1_4; if (j >= n2_4) return; in = in2; out = out2; }
  float4 f = ((const float4*)in)[j];
  s16x4 s;
  s.x = f2bf(f.x); s.y = f2bf(f.y); s.z = f2bf(f.z); s.w = f2bf(f.w);
  ((s16x4*)out)[j] = s;
}

// ========= generic BMt x BNT 8-phase bf16 NT GEMM (r5's PROVEN sync skeleton) =========
// r9: GEMM1 is covered by TWO one-exact-round launches of configs already proven on HW:
//   <256,256> on N=8192 (256 blocks, 64.4 us/round measured r8) and
//   <128,256> on N=4096 (256 blocks, 41.2 us/round measured r5).
// LDS-BW steady-state model (r5/r6/r8 fit ~55.5 B/cyc/CU): per-block gains of bigger
// wave tiles are real (+31% r8) but were eaten by the 1.5-round tail; exact-round grids
// recover them. Sync skeleton unchanged (proven r5/r8); loads/tile L = 2*(BMt/128)+2*BH;
// vmcnt(L) at ph4/ph8; cross-wave certification = per-wave counted wait BEFORE barrier.
// XCD 2D-chunk mapping (requires (N/BNT)%8==0). Granule swizzle g^=(row>>1)&7 via
// inverse-permuted global source (0 bank conflicts r2-r8).
template <int BMt, int BNT, int CMODE>
__global__ __launch_bounds__(512, 2) void gemm8p(
    const short* __restrict__ A, const short* __restrict__ Bw, void* __restrict__ Cp,
    int K, int N, int ldc) {
  constexpr int BH  = BNT / 128;   // B half-tiles (1 or 2)
  constexpr int NJ  = BNT / 64;    // per-wave N frags (2 or 4)
  constexpr int NJH = NJ / 2;      // N frags per quadrant
  constexpr int MF  = BMt / 64;    // per-wave M frags per half (2 or 4)
  constexpr int AST = BMt / 64;    // stA sweeps
  constexpr int LT  = 2 * (BMt / 128) + 2 * BH;   // loads per K-tile
  __shared__ short Al[2][BMt * 64];
  __shared__ short Bl[2][BH][128 * 64];
  const int tid  = threadIdx.x;
  const int lane = tid & 63;
  const int quad = lane >> 4;
  const int col  = lane & 15;
  const int wave = tid >> 6;
  const int wm   = wave >> 2;
  const int wn   = wave & 3;

  // XCD 2D-chunk mapping (requires nbn % 8 == 0)
  const int nbn = N / BNT;
  const int nbm = gridDim.x / nbn;
  const int xcd = blockIdx.x & 7;
  const int u   = blockIdx.x >> 3;
  const int m0  = (u % nbm) * BMt;
  const int n0  = (xcd * (nbn >> 3) + u / nbm) * BNT;

  const int NT = K >> 6;

  f32x4 acc[2 * MF][NJ] = {};
  bf16x8 a[MF][2], b0[NJH][2], b1[NJH][2];

  auto stA = [&](int t, int buf) {
#pragma unroll
    for (int r = 0; r < AST; ++r) {
      int idx = r * 512 + tid;
      int row = idx >> 3;
      int g   = idx & 7;
      int gs  = g ^ ((row >> 1) & 7);
      const short* ga = A + (size_t)(m0 + row) * K + t * 64 + gs * 8;
      __builtin_amdgcn_global_load_lds((const AS1 unsigned*)ga,
                                       (AS3 unsigned*)&Al[buf][idx * 8], 16, 0, 0);
    }
  };
  auto stB = [&](int t, int buf, int h) {
#pragma unroll
    for (int r = 0; r < 2; ++r) {
      int idx = r * 512 + tid;
      int row = idx >> 3;
      int g   = idx & 7;
      int gs  = g ^ ((row >> 1) & 7);
      const short* gb = Bw + (size_t)(n0 + h * 128 + row) * K + t * 64 + gs * 8;
      __builtin_amdgcn_global_load_lds((const AS1 unsigned*)gb,
                                       (AS3 unsigned*)&Bl[buf][h][idx * 8], 16, 0, 0);
    }
  };
  auto rdA = [&](int buf, int mh) {
#pragma unroll
    for (int i = 0; i < MF; ++i) {
      int rh = wm * (BMt / 2) + (mh * MF + i) * 16 + col;
#pragma unroll
      for (int kf = 0; kf < 2; ++kf)
        a[i][kf] =
            *(const bf16x8*)&Al[buf][rh * 64 + (((kf * 4 + quad) ^ ((rh >> 1) & 7)) * 8)];
    }
  };
  auto rdB = [&](int buf, int nh, bf16x8 (&bb)[NJH][2]) {
#pragma unroll
    for (int j = 0; j < NJH; ++j) {
      int br = wn * (BNT / 4) + nh * (BNT / 8) + j * 16 + col;
      int bh = br >> 7, rh = br & 127;
#pragma unroll
      for (int kf = 0; kf < 2; ++kf)
        bb[j][kf] =
            *(const bf16x8*)&Bl[buf][bh][rh * 64 + (((kf * 4 + quad) ^ ((rh >> 1) & 7)) * 8)];
    }
  };
  auto mm = [&](auto MH, auto NHc, bf16x8 (&bb)[NJH][2]) {
    constexpr int mh = MH.v, nh = NHc.v;
    __builtin_amdgcn_s_setprio(1);
#pragma unroll
    for (int i = 0; i < MF; ++i)
#pragma unroll
      for (int j = 0; j < NJH; ++j)
#pragma unroll
        for (int kf = 0; kf < 2; ++kf)
          acc[mh * MF + i][nh * NJH + j] = __builtin_amdgcn_mfma_f32_16x16x32_bf16(
              a[i][kf], bb[j][kf], acc[mh * MF + i][nh * NJH + j], 0, 0, 0);
    __builtin_amdgcn_s_setprio(0);
  };
#define LGK() do { asm volatile("s_waitcnt lgkmcnt(0)"); __builtin_amdgcn_sched_barrier(0); } while (0)
#define BAR() __builtin_amdgcn_s_barrier()
  auto vmc = [] {
    if constexpr (LT == 8)      asm volatile("s_waitcnt vmcnt(8)" ::: "memory");
    else if constexpr (LT == 6) asm volatile("s_waitcnt vmcnt(6)" ::: "memory");
    else                        asm volatile("s_waitcnt vmcnt(4)" ::: "memory");
  };

  // prologue: stage tile0 -> buf0, tile1 -> buf1; retire tile0, keep tile1 in flight
#pragma unroll
  for (int h = 0; h < BH; ++h) stB(0, 0, h);
  stA(0, 0);
#pragma unroll
  for (int h = 0; h < BH; ++h) stB(1, 1, h);
  stA(1, 1);
  vmc();
  BAR();

  for (int i = 0; i < (NT >> 1); ++i) {
    const int t  = 2 * i;
    const int tA = (t + 2 < NT) ? t + 2 : NT - 2;   // clamped restage: identical bytes
    const int tB = (t + 3 < NT) ? t + 3 : NT - 1;
    // ph1
    rdA(0, 0); rdB(0, 0, b0);
    BAR(); LGK();
    mm(IC<0>{}, IC<0>{}, b0);
    BAR();
    // ph2
    rdB(0, 1, b1);
    BAR(); LGK();
    mm(IC<0>{}, IC<1>{}, b1);
    BAR();
    // ph3  (B-buf0 dead since ph2-LGK)
    rdA(0, 1);
    stB(tA, 0, 0);
    BAR(); LGK();
    mm(IC<1>{}, IC<1>{}, b1);
    BAR();
    // ph4  (A-buf0 dead since ph3-LGK)
    if constexpr (BH >= 2) stB(tA, 0, 1);
    stA(tA, 0);
    BAR();
    mm(IC<1>{}, IC<0>{}, b0);
    vmc();
    BAR();
    // ph5
    rdA(1, 0); rdB(1, 0, b0);
    BAR(); LGK();
    mm(IC<0>{}, IC<0>{}, b0);
    BAR();
    // ph6
    rdB(1, 1, b1);
    BAR(); LGK();
    mm(IC<0>{}, IC<1>{}, b1);
    BAR();
    // ph7  (B-buf1 dead since ph6-LGK)
    rdA(1, 1);
    stB(tB, 1, 0);
    if constexpr (BH >= 2) stB(tB, 1, 1);
    BAR(); LGK();
    mm(IC<1>{}, IC<1>{}, b1);
    BAR();
    // ph8  (A-buf1 dead since ph7-LGK)
    stA(tB, 1);
    BAR();
    mm(IC<1>{}, IC<0>{}, b0);
    vmc();
    BAR();
  }
#undef LGK
#undef BAR

  // epilogue: C/D layout col=lane&15, row=quad*4+reg
#pragma unroll
  for (int mi = 0; mi < 2 * MF; ++mi)
#pragma unroll
    for (int nj = 0; nj < NJ; ++nj)
#pragma unroll
      for (int r = 0; r < 4; ++r) {
        int rr = m0 + wm * (BMt / 2) + mi * 16 + quad * 4 + r;
        int cc = n0 + wn * (BNT / 4) + nj * 16 + col;
        if (CMODE == 1)
          ((float*)Cp)[(size_t)rr * ldc + cc] = acc[mi][nj][r];
        else
          ((short*)Cp)[(size_t)rr * ldc + cc] = f2bf(acc[mi][nj][r]);
      }
}

// ---------------- NT GEMM: A(bf16) * B^T(f32) — fallback path only ----------------
#define BM 128
#define BK 32

template <int BNT, int CMODE>
__global__ __launch_bounds__(256, 2) void gemm_nt_f32w(
    const short* __restrict__ A, const float* __restrict__ B, void* __restrict__ Cp,
    int K, int ldc) {
  __shared__ short Alds[2][BM * BK];
  __shared__ short Blds[2][BNT * BK];
  constexpr int WN  = BNT / 2;
  constexpr int NJ  = WN / 16;
  constexpr int BCH = (BNT * 4) / 256;
  const int tid  = threadIdx.x;
  const int lane = tid & 63;
  const int quad = lane >> 4;
  const int col  = lane & 15;
  const int wave = tid >> 6;
  const int m0 = blockIdx.y * BM;
  const int n0 = blockIdx.x * BNT;
  const int wm = (wave & 1) * 64;
  const int wn = (wave >> 1) * WN;

  f32x4 acc[4][NJ] = {};
  float4 breg[BCH][2];

  const int nk = K / BK;

  auto b_issue = [&](int k0) {
#pragma unroll
    for (int it = 0; it < BCH; ++it) {
      int idx = it * 256 + tid;
      int row = idx >> 2;
      int c   = idx & 3;
      const float* gb = B + (size_t)(n0 + row) * K + k0 + c * 8;
      breg[it][0] = *(const float4*)gb;
      breg[it][1] = *(const float4*)(gb + 4);
    }
  };
  auto a_issue = [&](int k0, int buf) {
#pragma unroll
    for (int it = 0; it < 2; ++it) {
      int idx = it * 256 + tid;
      int row = idx >> 2;
      int c   = idx & 3;
      int cs  = c ^ ((row >> 1) & 3);
      const short* ga = A + (size_t)(m0 + row) * K + k0 + cs * 8;
      __builtin_amdgcn_global_load_lds((const AS1 unsigned*)ga,
                                       (AS3 unsigned*)&Alds[buf][idx * 8], 16, 0, 0);
    }
  };
  auto b_write = [&](int buf) {
#pragma unroll
    for (int it = 0; it < BCH; ++it) {
      int idx = it * 256 + tid;
      int row = idx >> 2;
      int c   = idx & 3;
      int cw  = c ^ ((row >> 1) & 3);
      union { unsigned u[4]; bf16x8 v; } pk;
      pk.u[0] = pk2bf(breg[it][0].x, breg[it][0].y);
      pk.u[1] = pk2bf(breg[it][0].z, breg[it][0].w);
      pk.u[2] = pk2bf(breg[it][1].x, breg[it][1].y);
      pk.u[3] = pk2bf(breg[it][1].z, breg[it][1].w);
      *(bf16x8*)&Blds[buf][(row * 4 + cw) * 8] = pk.v;
    }
  };
  auto compute = [&](int buf) {
    bf16x8 a[4], b[NJ];
#pragma unroll
    for (int i = 0; i < 4; ++i) {
      int row = wm + i * 16 + col;
      a[i] = *(const bf16x8*)&Alds[buf][(row * 4 + (quad ^ ((row >> 1) & 3))) * 8];
    }
#pragma unroll
    for (int j = 0; j < NJ; ++j) {
      int row = wn + j * 16 + col;
      b[j] = *(const bf16x8*)&Blds[buf][(row * 4 + (quad ^ ((row >> 1) & 3))) * 8];
    }
#pragma unroll
    for (int i = 0; i < 4; ++i)
#pragma unroll
      for (int j = 0; j < NJ; ++j)
        acc[i][j] = __builtin_amdgcn_mfma_f32_16x16x32_bf16(a[i], b[j], acc[i][j], 0, 0, 0);
  };

  b_issue(0);
  a_issue(0, 0);
  b_write(0);
  __syncthreads();

  for (int t = 0; t < nk - 1; ++t) {
    const int cur = t & 1;
    b_issue((t + 1) * BK);
    a_issue((t + 1) * BK, cur ^ 1);
    compute(cur);
    b_write(cur ^ 1);
    __syncthreads();
  }
  compute((nk - 1) & 1);

#pragma unroll
  for (int i = 0; i < 4; ++i)
#pragma unroll
    for (int j = 0; j < NJ; ++j)
#pragma unroll
      for (int r = 0; r < 4; ++r) {
        int rr = m0 + wm + i * 16 + quad * 4 + r;
        int cc = n0 + wn + j * 16 + col;
        if (CMODE == 1)
          ((float*)Cp)[(size_t)rr * ldc + cc] = acc[i][j][r];
        else
          ((short*)Cp)[(size_t)rr * ldc + cc] = f2bf(acc[i][j][r]);
      }
}

// --- fused: RMSNorm+RoPE q,k [0,32768) + V pack [32768,33792) + o_proj convert [33792,...) ---
__global__ void normrope_packv_kernel(short* __restrict__ qkv,
                                      const int* __restrict__ positions,
                                      const float* __restrict__ qw,
                                      const float* __restrict__ kw,
                                      short* __restrict__ vtp,
                                      const float* __restrict__ ow,
                                      short* __restrict__ ow_bf,
                                      int n3_4) {
  __shared__ short T[64][136];
  if (blockIdx.x < 32768) {
    int item = blockIdx.x * 4 + (threadIdx.x >> 6);
    int lane = threadIdx.x & 63;
    int head  = item & 31;
    int which = (item >> 5) & 1;
    int s     = item >> 6;
    const float* w = which ? kw : qw;
    short* base = qkv + (size_t)s * QKV_O + which * OD + head * HD;

    float x1 = bf2f(base[lane]);
    float x2 = bf2f(base[lane + 64]);
    float ss = x1 * x1 + x2 * x2;
#pragma unroll
    for (int d = 32; d; d >>= 1) ss += __shfl_xor(ss, d);
    float r = rsqrtf(ss * (1.0f / 128.0f) + 1e-5f);
    float xn1 = x1 * r * w[lane];
    float xn2 = x2 * r * w[lane + 64];

    float pos = (float)positions[s];
    float inv_freq = exp2f((float)lane * (-13.287712379549449f / 64.0f));
    float f = pos * inv_freq;
    float c = cosf(f), sn = sinf(f);
    float sc = which ? 1.0f : 0.12751863738f;   // q: fold scale*log2(e)
    base[lane]      = f2bf((xn1 * c - xn2 * sn) * sc);
    base[lane + 64] = f2bf((xn2 * c + xn1 * sn) * sc);
  } else if (blockIdx.x < 33792) {
    int bid2 = blockIdx.x - 32768;
    const int h  = bid2 & 31;
    const int kt = bid2 >> 5;
    const int tid = threadIdx.x;
    {
      int rr = tid >> 2;
      int db = (tid & 3) * 32;
      const short* src = qkv + (size_t)(kt * 64 + rr) * QKV_O + 2 * OD + h * HD + db;
#pragma unroll
      for (int i = 0; i < 4; ++i)
        *(bf16x8*)&T[rr][db + i * 8] = *(const bf16x8*)(src + i * 8);
    }
    __syncthreads();
    {
      int d  = tid >> 1;
      int k0 = (tid & 1) * 32;
      short* dst = vtp + (((size_t)h * 32 + kt) * 128 + d) * 64 + k0;
#pragma unroll
      for (int c = 0; c < 4; ++c) {
        bf16x8 v;
#pragma unroll
        for (int j = 0; j < 8; ++j) v[j] = T[k0 + c * 8 + j][d];
        *(bf16x8*)&dst[c * 8] = v;
      }
    }
  } else {
    int i = (blockIdx.x - 33792) * 256 + threadIdx.x;
    if (i >= n3_4) return;
    float4 f = ((const float4*)ow)[i];
    s16x4 s;
    s.x = f2bf(f.x); s.y = f2bf(f.y); s.z = f2bf(f.z); s.w = f2bf(f.w);
    ((s16x4*)ow_bf)[i] = s;
  }
}

// ---------------- flash attention (causal), Bq=64/Bk=64 paired, dbuf + async-stage ------
// r6 exact (proven): dbuf, loads-before-barrier, writeKV-after-compute, T5 setprio,
// T13 defer-max THR=8.
__global__ __launch_bounds__(256, 2) void attn_kernel(
    const short* __restrict__ qkv, const short* __restrict__ vtp, short* __restrict__ obuf) {
  __shared__ short Klds[2][64 * 128];   // 2 x 16 KB
  __shared__ short Vt[2][128 * 64];     // 2 x 16 KB
  __shared__ short Plds[4][16 * 64];    // 8 KB

  const int tid  = threadIdx.x;
  const int lane = tid & 63;
  const int wave = tid >> 6;
  const int quad = lane >> 4;
  const int col  = lane & 15;
  const int h    = blockIdx.y;

  const int kr  = tid >> 2;
  const int kcb = (tid & 3) * 32;
  const int vd  = tid >> 1;
  const int vcb = (tid & 1) * 32;

  bf16x8 kreg[4], vreg[4];

  auto loadK = [&](int kt) {
    const short* kp = qkv + (size_t)(kt * 64 + kr) * QKV_O + OD + h * HD + kcb;
#pragma unroll
    for (int i = 0; i < 4; ++i) kreg[i] = *(const bf16x8*)(kp + i * 8);
  };
  auto loadV = [&](int kt) {
    const short* vp = vtp + (((size_t)h * 32 + kt) * 128 + vd) * 64 + vcb;
#pragma unroll
    for (int i = 0; i < 4; ++i) vreg[i] = *(const bf16x8*)(vp + i * 8);
  };
  auto writeKV = [&](int buf) {
#pragma unroll
    for (int i = 0; i < 4; ++i) {
      int swz = ((tid & 3) * 4 + i) ^ (kr & 15);
      *(bf16x8*)&Klds[buf][kr * 128 + swz * 8] = kreg[i];
    }
#pragma unroll
    for (int i = 0; i < 4; ++i) {
      int swz = ((tid & 1) * 4 + i) ^ (vd & 7);
      *(bf16x8*)&Vt[buf][vd * 64 + swz * 8] = vreg[i];
    }
  };

#pragma unroll 1
  for (int half = 0; half < 2; ++half) {
    const int qt = half == 0 ? blockIdx.x : 31 - blockIdx.x;   // paired: 33 k-iters/block
    const int qbase = qt * 64 + wave * 16;

    bf16x8 qf[4];
#pragma unroll
    for (int kf = 0; kf < 4; ++kf)
      qf[kf] = *(const bf16x8*)(qkv + (size_t)(qbase + col) * QKV_O + h * HD + kf * 32 + quad * 8);

    f32x4 o[8] = {};
    float m_r[4], l_i[4];
#pragma unroll
    for (int r = 0; r < 4; ++r) { m_r[r] = -1e30f; l_i[r] = 0.f; }

    loadK(0); loadV(0);
    __syncthreads();
    writeKV(0);

#pragma unroll 1
    for (int kt = 0; kt <= qt; ++kt) {
      const int cur = kt & 1;
      if (kt < qt) { loadK(kt + 1); loadV(kt + 1); }   // T14: issue early
      __syncthreads();                                  // buf[cur] writes visible

      f32x4 sfr[4];
      __builtin_amdgcn_s_setprio(1);
#pragma unroll
      for (int nf = 0; nf < 4; ++nf) {
        f32x4 acc = {};
#pragma unroll
        for (int kf = 0; kf < 4; ++kf) {
          bf16x8 b = *(const bf16x8*)&Klds[cur][(nf * 16 + col) * 128 + ((kf * 4 + quad) ^ col) * 8];
          acc = __builtin_amdgcn_mfma_f32_16x16x32_bf16(qf[kf], b, acc, 0, 0, 0);
        }
        sfr[nf] = acc;
      }
      __builtin_amdgcn_s_setprio(0);

      if (kt == qt) {
#pragma unroll
        for (int nf = 0; nf < 4; ++nf)
#pragma unroll
          for (int r = 0; r < 4; ++r) {
            int key = kt * 64 + nf * 16 + col;
            int qg  = qbase + quad * 4 + r;
            if (key > qg) sfr[nf][r] = -1e30f;
          }
      }

#pragma unroll
      for (int r = 0; r < 4; ++r) {
        float mt = fmaxf(fmaxf(sfr[0][r], sfr[1][r]), fmaxf(sfr[2][r], sfr[3][r]));
#pragma unroll
        for (int d = 8; d; d >>= 1) mt = fmaxf(mt, __shfl_xor(mt, d));
        float mnew = fmaxf(m_r[r], mt);
        bool defer = __all(mnew - m_r[r] <= 8.0f);
        if (defer) mnew = m_r[r];
        float alpha = exp2f(m_r[r] - mnew);
        float ps = 0.f;
#pragma unroll
        for (int nf = 0; nf < 4; ++nf) {
          float p = exp2f(sfr[nf][r] - mnew);
          sfr[nf][r] = p;
          ps += p;
        }
        l_i[r] = l_i[r] * alpha + ps;
        if (!defer) {
#pragma unroll
          for (int nf = 0; nf < 8; ++nf) o[nf][r] *= alpha;
          m_r[r] = mnew;
        }
      }

#pragma unroll
      for (int nf = 0; nf < 4; ++nf)
#pragma unroll
        for (int r = 0; r < 4; ++r) {
          int row = quad * 4 + r;
          int key = nf * 16 + col;
          Plds[wave][row * 64 + ((key >> 3) ^ (row & 7)) * 8 + (key & 7)] = f2bf(sfr[nf][r]);
        }

      bf16x8 pa[2];
#pragma unroll
      for (int kf = 0; kf < 2; ++kf)
        pa[kf] = *(const bf16x8*)&Plds[wave][col * 64 + ((kf * 4 + quad) ^ (col & 7)) * 8];
      __builtin_amdgcn_s_setprio(1);
#pragma unroll
      for (int nf = 0; nf < 8; ++nf)
#pragma unroll
        for (int kf = 0; kf < 2; ++kf) {
          bf16x8 vb = *(const bf16x8*)&Vt[cur][(nf * 16 + col) * 64 + ((kf * 4 + quad) ^ (col & 7)) * 8];
          o[nf] = __builtin_amdgcn_mfma_f32_16x16x32_bf16(pa[kf], vb, o[nf], 0, 0, 0);
        }
      __builtin_amdgcn_s_setprio(0);

      if (kt < qt) writeKV(cur ^ 1);
    }

#pragma unroll
    for (int r = 0; r < 4; ++r) {
      float lt = l_i[r];
#pragma unroll
      for (int d = 8; d; d >>= 1) lt += __shfl_xor(lt, d);
      float inv = 1.0f / lt;
      int sg = qbase + quad * 4 + r;
#pragma unroll
      for (int nf = 0; nf < 8; ++nf)
        obuf[(size_t)sg * OD + h * HD + nf * 16 + col] = f2bf(o[nf][r] * inv);
    }
  }
}

// ---------------- launcher ----------------
extern "C" void kernel_launch(void* const* d_in, const int* in_sizes, int n_in,
                              void* d_out, int out_size, void* d_ws, size_t ws_size,
                              hipStream_t stream) {
  (void)in_sizes; (void)n_in; (void)out_size;
  const float* hs   = (const float*)d_in[0];
  const int*   pos  = (const int*)d_in[1];
  const float* qkvw = (const float*)d_in[2];
  const float* qw   = (const float*)d_in[3];
  const float* kw   = (const float*)d_in[4];
  const float* ow   = (const float*)d_in[5];
  float* out = (float*)d_out;

  // ws plan: [0,48M) qkvb | [48M,64M) obuf | [64M,112M) qkvw_bf, later ow_bf (fast path)
  char* ws = (char*)d_ws;
  short* qkvb    = (short*)(ws);
  short* obuf    = (short*)(ws + 50331648);
  short* qkvw_bf = (short*)(ws + 67108864);
  short* ow_bf   = (short*)(ws + 67108864);   // reuses qkvw_bf region after GEMM1
  short* hsb  = (short*)d_out;
  short* vtp  = (short*)d_out;

  const bool fast = ws_size >= (size_t)117440512;

  if (fast) {
    // 1) convert hidden_states AND qkv_w -> bf16 in one launch
    int n1 = (S_LEN * HID) / 4, n2 = (QKV_O * HID) / 4;
    convert2_kernel<<<(n1 + n2 + 255) / 256, 256, 0, stream>>>(hs, hsb, n1, qkvw, qkvw_bf, n2);
    // 2) qkv = hs @ qkv_w^T, TWO one-exact-round slices:
    //    slice 1: N=[0,8192)     256x256 tiles -> 8*32  = 256 blocks (1 round, r8-proven)
    //    slice 2: N=[8192,12288) 128x256 tiles -> 16*16 = 256 blocks (1 round, r5-proven)
    gemm8p<256, 256, 0><<<(S_LEN / 256) * (8192 / 256), 512, 0, stream>>>(
        hsb, qkvw_bf, qkvb, HID, 8192, QKV_O);
    gemm8p<128, 256, 0><<<(S_LEN / 128) * (4096 / 256), 512, 0, stream>>>(
        hsb, qkvw_bf + (size_t)8192 * HID, qkvb + 8192, HID, 4096, QKV_O);
    // 3+4+2b) RMSNorm+RoPE, V pack, AND o_proj convert (into now-dead qkvw_bf), one launch
    int n3 = (HID * OD) / 4;
    normrope_packv_kernel<<<(S_LEN * 2 * NH) / 4 + NH * (S_LEN / 64) + n3 / 256,
                            256, 0, stream>>>(qkvb, pos, qw, kw, vtp, ow, ow_bf, n3);
  } else {
    int n1 = (S_LEN * HID) / 4;
    convert2_kernel<<<(n1 + 255) / 256, 256, 0, stream>>>(hs, hsb, n1, hs, hsb, 0);
    gemm_nt_f32w<128, 0><<<dim3(QKV_O / 128, S_LEN / BM), 256, 0, stream>>>(
        hsb, qkvw, qkvb, HID, QKV_O);
    normrope_packv_kernel<<<(S_LEN * 2 * NH) / 4 + NH * (S_LEN / 64),
                            256, 0, stream>>>(qkvb, pos, qw, kw, vtp, hs, (short*)d_ws, 0);
  }

  // 5) causal flash attention -> obuf
  attn_kernel<<<dim3(16, NH), 256, 0, stream>>>(qkvb, vtp, obuf);

  // 6) out = obuf @ o_proj_w^T (fp32 C)
  if (fast) {
    // 128x128 tiles -> 256 blocks (2 blocks/CU, fully resident), K=4096 (r5-proven)
    gemm8p<128, 128, 1><<<(S_LEN / 128) * (HID / 128), 512, 0, stream>>>(
        obuf, ow_bf, out, OD, HID, HID);
  } else {
    gemm_nt_f32w<64, 1><<<dim3(HID / 64, S_LEN / BM), 256, 0, stream>>>(
        obuf, ow, out, OD, HID);
  }
}

// Round 10
// 464.225 us; speedup vs baseline: 1.0581x; 1.0235x over previous
//
#include <hip/hip_runtime.h>
#include <cstdint>
#include <cstddef>

// ---- problem constants ----
static constexpr int S_LEN = 2048;
static constexpr int HID   = 2048;
static constexpr int NH    = 32;
static constexpr int HD    = 128;
static constexpr int OD    = 4096;    // NH*HD
static constexpr int QKV_O = 12288;   // 3*OD

#define AS1 __attribute__((address_space(1)))
#define AS3 __attribute__((address_space(3)))

typedef __attribute__((ext_vector_type(8))) short bf16x8;
typedef __attribute__((ext_vector_type(4))) float f32x4;
typedef __attribute__((ext_vector_type(4))) short s16x4;

template <int V> struct IC { static constexpr int v = V; };

__device__ __forceinline__ short f2bf(float f) {
  unsigned u = __float_as_uint(f);
  unsigned r = (u + 0x7fffu + ((u >> 16) & 1u)) >> 16;   // RNE
  return (short)r;
}
__device__ __forceinline__ float bf2f(short s) {
  return __uint_as_float(((unsigned)(unsigned short)s) << 16);
}
__device__ __forceinline__ unsigned pk2bf(float a, float b) {
  return __builtin_amdgcn_perm(__float_as_uint(b), __float_as_uint(a), 0x07060302u);
}

// ---------------- fp32 -> bf16 convert: two regions in one launch ----------------
__global__ void convert2_kernel(const float* __restrict__ in1, short* __restrict__ out1, int n1_4,
                                const float* __restrict__ in2, short* __restrict__ out2, int n2_4) {
  int i = blockIdx.x * blockDim.x + threadIdx.x;
  const float* in; short* out; int j;
  if (i < n1_4) { in = in1; out = out1; j = i; }
  else { j = i - n1_4; if (j >= n2_4) return; in = in2; out = out2; }
  float4 f = ((const float4*)in)[j];
  s16x4 s;
  s.x = f2bf(f.x); s.y = f2bf(f.y); s.z = f2bf(f.z); s.w = f2bf(f.w);
  ((s16x4*)out)[j] = s;
}

// ========= generic BMt x BNT 8-phase bf16 NT GEMM (r5's PROVEN sync skeleton) =========
// GEMM1 = two one-exact-round slices (r9-proven): <256,256> on N=8192 + <128,256> on
// N=4096. LDS-BW model: ~55.5 B/cyc/CU steady state; exact-round grids avoid the tail.
// Sync skeleton r5/r8-proven; loads/tile L = 2*(BMt/128)+2*BH; vmcnt(L) at ph4/ph8;
// cross-wave certification = per-wave counted wait BEFORE barrier.
// XCD 2D-chunk mapping (requires (N/BNT)%8==0). Granule swizzle g^=(row>>1)&7 via
// inverse-permuted global source (0 bank conflicts r2-r9).
template <int BMt, int BNT, int CMODE>
__global__ __launch_bounds__(512, 2) void gemm8p(
    const short* __restrict__ A, const short* __restrict__ Bw, void* __restrict__ Cp,
    int K, int N, int ldc) {
  constexpr int BH  = BNT / 128;   // B half-tiles (1 or 2)
  constexpr int NJ  = BNT / 64;    // per-wave N frags (2 or 4)
  constexpr int NJH = NJ / 2;      // N frags per quadrant
  constexpr int MF  = BMt / 64;    // per-wave M frags per half (2 or 4)
  constexpr int AST = BMt / 64;    // stA sweeps
  constexpr int LT  = 2 * (BMt / 128) + 2 * BH;   // loads per K-tile
  __shared__ short Al[2][BMt * 64];
  __shared__ short Bl[2][BH][128 * 64];
  const int tid  = threadIdx.x;
  const int lane = tid & 63;
  const int quad = lane >> 4;
  const int col  = lane & 15;
  const int wave = tid >> 6;
  const int wm   = wave >> 2;
  const int wn   = wave & 3;

  // XCD 2D-chunk mapping (requires nbn % 8 == 0)
  const int nbn = N / BNT;
  const int nbm = gridDim.x / nbn;
  const int xcd = blockIdx.x & 7;
  const int u   = blockIdx.x >> 3;
  const int m0  = (u % nbm) * BMt;
  const int n0  = (xcd * (nbn >> 3) + u / nbm) * BNT;

  const int NT = K >> 6;

  f32x4 acc[2 * MF][NJ] = {};
  bf16x8 a[MF][2], b0[NJH][2], b1[NJH][2];

  auto stA = [&](int t, int buf) {
#pragma unroll
    for (int r = 0; r < AST; ++r) {
      int idx = r * 512 + tid;
      int row = idx >> 3;
      int g   = idx & 7;
      int gs  = g ^ ((row >> 1) & 7);
      const short* ga = A + (size_t)(m0 + row) * K + t * 64 + gs * 8;
      __builtin_amdgcn_global_load_lds((const AS1 unsigned*)ga,
                                       (AS3 unsigned*)&Al[buf][idx * 8], 16, 0, 0);
    }
  };
  auto stB = [&](int t, int buf, int h) {
#pragma unroll
    for (int r = 0; r < 2; ++r) {
      int idx = r * 512 + tid;
      int row = idx >> 3;
      int g   = idx & 7;
      int gs  = g ^ ((row >> 1) & 7);
      const short* gb = Bw + (size_t)(n0 + h * 128 + row) * K + t * 64 + gs * 8;
      __builtin_amdgcn_global_load_lds((const AS1 unsigned*)gb,
                                       (AS3 unsigned*)&Bl[buf][h][idx * 8], 16, 0, 0);
    }
  };
  auto rdA = [&](int buf, int mh) {
#pragma unroll
    for (int i = 0; i < MF; ++i) {
      int rh = wm * (BMt / 2) + (mh * MF + i) * 16 + col;
#pragma unroll
      for (int kf = 0; kf < 2; ++kf)
        a[i][kf] =
            *(const bf16x8*)&Al[buf][rh * 64 + (((kf * 4 + quad) ^ ((rh >> 1) & 7)) * 8)];
    }
  };
  auto rdB = [&](int buf, int nh, bf16x8 (&bb)[NJH][2]) {
#pragma unroll
    for (int j = 0; j < NJH; ++j) {
      int br = wn * (BNT / 4) + nh * (BNT / 8) + j * 16 + col;
      int bh = br >> 7, rh = br & 127;
#pragma unroll
      for (int kf = 0; kf < 2; ++kf)
        bb[j][kf] =
            *(const bf16x8*)&Bl[buf][bh][rh * 64 + (((kf * 4 + quad) ^ ((rh >> 1) & 7)) * 8)];
    }
  };
  auto mm = [&](auto MH, auto NHc, bf16x8 (&bb)[NJH][2]) {
    constexpr int mh = MH.v, nh = NHc.v;
    __builtin_amdgcn_s_setprio(1);
#pragma unroll
    for (int i = 0; i < MF; ++i)
#pragma unroll
      for (int j = 0; j < NJH; ++j)
#pragma unroll
        for (int kf = 0; kf < 2; ++kf)
          acc[mh * MF + i][nh * NJH + j] = __builtin_amdgcn_mfma_f32_16x16x32_bf16(
              a[i][kf], bb[j][kf], acc[mh * MF + i][nh * NJH + j], 0, 0, 0);
    __builtin_amdgcn_s_setprio(0);
  };
#define LGK() do { asm volatile("s_waitcnt lgkmcnt(0)"); __builtin_amdgcn_sched_barrier(0); } while (0)
#define BAR() __builtin_amdgcn_s_barrier()
  auto vmc = [] {
    if constexpr (LT == 8)      asm volatile("s_waitcnt vmcnt(8)" ::: "memory");
    else if constexpr (LT == 6) asm volatile("s_waitcnt vmcnt(6)" ::: "memory");
    else                        asm volatile("s_waitcnt vmcnt(4)" ::: "memory");
  };

  // prologue: stage tile0 -> buf0, tile1 -> buf1; retire tile0, keep tile1 in flight
#pragma unroll
  for (int h = 0; h < BH; ++h) stB(0, 0, h);
  stA(0, 0);
#pragma unroll
  for (int h = 0; h < BH; ++h) stB(1, 1, h);
  stA(1, 1);
  vmc();
  BAR();

  for (int i = 0; i < (NT >> 1); ++i) {
    const int t  = 2 * i;
    const int tA = (t + 2 < NT) ? t + 2 : NT - 2;   // clamped restage: identical bytes
    const int tB = (t + 3 < NT) ? t + 3 : NT - 1;
    // ph1
    rdA(0, 0); rdB(0, 0, b0);
    BAR(); LGK();
    mm(IC<0>{}, IC<0>{}, b0);
    BAR();
    // ph2
    rdB(0, 1, b1);
    BAR(); LGK();
    mm(IC<0>{}, IC<1>{}, b1);
    BAR();
    // ph3  (B-buf0 dead since ph2-LGK)
    rdA(0, 1);
    stB(tA, 0, 0);
    BAR(); LGK();
    mm(IC<1>{}, IC<1>{}, b1);
    BAR();
    // ph4  (A-buf0 dead since ph3-LGK)
    if constexpr (BH >= 2) stB(tA, 0, 1);
    stA(tA, 0);
    BAR();
    mm(IC<1>{}, IC<0>{}, b0);
    vmc();
    BAR();
    // ph5
    rdA(1, 0); rdB(1, 0, b0);
    BAR(); LGK();
    mm(IC<0>{}, IC<0>{}, b0);
    BAR();
    // ph6
    rdB(1, 1, b1);
    BAR(); LGK();
    mm(IC<0>{}, IC<1>{}, b1);
    BAR();
    // ph7  (B-buf1 dead since ph6-LGK)
    rdA(1, 1);
    stB(tB, 1, 0);
    if constexpr (BH >= 2) stB(tB, 1, 1);
    BAR(); LGK();
    mm(IC<1>{}, IC<1>{}, b1);
    BAR();
    // ph8  (A-buf1 dead since ph7-LGK)
    stA(tB, 1);
    BAR();
    mm(IC<1>{}, IC<0>{}, b0);
    vmc();
    BAR();
  }
#undef LGK
#undef BAR

  // epilogue: C/D layout col=lane&15, row=quad*4+reg
#pragma unroll
  for (int mi = 0; mi < 2 * MF; ++mi)
#pragma unroll
    for (int nj = 0; nj < NJ; ++nj)
#pragma unroll
      for (int r = 0; r < 4; ++r) {
        int rr = m0 + wm * (BMt / 2) + mi * 16 + quad * 4 + r;
        int cc = n0 + wn * (BNT / 4) + nj * 16 + col;
        if (CMODE == 1)
          ((float*)Cp)[(size_t)rr * ldc + cc] = acc[mi][nj][r];
        else
          ((short*)Cp)[(size_t)rr * ldc + cc] = f2bf(acc[mi][nj][r]);
      }
}

// ---------------- NT GEMM: A(bf16) * B^T(f32) — fallback path only ----------------
#define BM 128
#define BK 32

template <int BNT, int CMODE>
__global__ __launch_bounds__(256, 2) void gemm_nt_f32w(
    const short* __restrict__ A, const float* __restrict__ B, void* __restrict__ Cp,
    int K, int ldc) {
  __shared__ short Alds[2][BM * BK];
  __shared__ short Blds[2][BNT * BK];
  constexpr int WN  = BNT / 2;
  constexpr int NJ  = WN / 16;
  constexpr int BCH = (BNT * 4) / 256;
  const int tid  = threadIdx.x;
  const int lane = tid & 63;
  const int quad = lane >> 4;
  const int col  = lane & 15;
  const int wave = tid >> 6;
  const int m0 = blockIdx.y * BM;
  const int n0 = blockIdx.x * BNT;
  const int wm = (wave & 1) * 64;
  const int wn = (wave >> 1) * WN;

  f32x4 acc[4][NJ] = {};
  float4 breg[BCH][2];

  const int nk = K / BK;

  auto b_issue = [&](int k0) {
#pragma unroll
    for (int it = 0; it < BCH; ++it) {
      int idx = it * 256 + tid;
      int row = idx >> 2;
      int c   = idx & 3;
      const float* gb = B + (size_t)(n0 + row) * K + k0 + c * 8;
      breg[it][0] = *(const float4*)gb;
      breg[it][1] = *(const float4*)(gb + 4);
    }
  };
  auto a_issue = [&](int k0, int buf) {
#pragma unroll
    for (int it = 0; it < 2; ++it) {
      int idx = it * 256 + tid;
      int row = idx >> 2;
      int c   = idx & 3;
      int cs  = c ^ ((row >> 1) & 3);
      const short* ga = A + (size_t)(m0 + row) * K + k0 + cs * 8;
      __builtin_amdgcn_global_load_lds((const AS1 unsigned*)ga,
                                       (AS3 unsigned*)&Alds[buf][idx * 8], 16, 0, 0);
    }
  };
  auto b_write = [&](int buf) {
#pragma unroll
    for (int it = 0; it < BCH; ++it) {
      int idx = it * 256 + tid;
      int row = idx >> 2;
      int c   = idx & 3;
      int cw  = c ^ ((row >> 1) & 3);
      union { unsigned u[4]; bf16x8 v; } pk;
      pk.u[0] = pk2bf(breg[it][0].x, breg[it][0].y);
      pk.u[1] = pk2bf(breg[it][0].z, breg[it][0].w);
      pk.u[2] = pk2bf(breg[it][1].x, breg[it][1].y);
      pk.u[3] = pk2bf(breg[it][1].z, breg[it][1].w);
      *(bf16x8*)&Blds[buf][(row * 4 + cw) * 8] = pk.v;
    }
  };
  auto compute = [&](int buf) {
    bf16x8 a[4], b[NJ];
#pragma unroll
    for (int i = 0; i < 4; ++i) {
      int row = wm + i * 16 + col;
      a[i] = *(const bf16x8*)&Alds[buf][(row * 4 + (quad ^ ((row >> 1) & 3))) * 8];
    }
#pragma unroll
    for (int j = 0; j < NJ; ++j) {
      int row = wn + j * 16 + col;
      b[j] = *(const bf16x8*)&Blds[buf][(row * 4 + (quad ^ ((row >> 1) & 3))) * 8];
    }
#pragma unroll
    for (int i = 0; i < 4; ++i)
#pragma unroll
      for (int j = 0; j < NJ; ++j)
        acc[i][j] = __builtin_amdgcn_mfma_f32_16x16x32_bf16(a[i], b[j], acc[i][j], 0, 0, 0);
  };

  b_issue(0);
  a_issue(0, 0);
  b_write(0);
  __syncthreads();

  for (int t = 0; t < nk - 1; ++t) {
    const int cur = t & 1;
    b_issue((t + 1) * BK);
    a_issue((t + 1) * BK, cur ^ 1);
    compute(cur);
    b_write(cur ^ 1);
    __syncthreads();
  }
  compute((nk - 1) & 1);

#pragma unroll
  for (int i = 0; i < 4; ++i)
#pragma unroll
    for (int j = 0; j < NJ; ++j)
#pragma unroll
      for (int r = 0; r < 4; ++r) {
        int rr = m0 + wm + i * 16 + quad * 4 + r;
        int cc = n0 + wn + j * 16 + col;
        if (CMODE == 1)
          ((float*)Cp)[(size_t)rr * ldc + cc] = acc[i][j][r];
        else
          ((short*)Cp)[(size_t)rr * ldc + cc] = f2bf(acc[i][j][r]);
      }
}

// --- fused: RMSNorm+RoPE q,k [0,32768) + V pack [32768,33792) + o_proj convert [33792,...) ---
__global__ void normrope_packv_kernel(short* __restrict__ qkv,
                                      const int* __restrict__ positions,
                                      const float* __restrict__ qw,
                                      const float* __restrict__ kw,
                                      short* __restrict__ vtp,
                                      const float* __restrict__ ow,
                                      short* __restrict__ ow_bf,
                                      int n3_4) {
  __shared__ short T[64][136];
  if (blockIdx.x < 32768) {
    int item = blockIdx.x * 4 + (threadIdx.x >> 6);
    int lane = threadIdx.x & 63;
    int head  = item & 31;
    int which = (item >> 5) & 1;
    int s     = item >> 6;
    const float* w = which ? kw : qw;
    short* base = qkv + (size_t)s * QKV_O + which * OD + head * HD;

    float x1 = bf2f(base[lane]);
    float x2 = bf2f(base[lane + 64]);
    float ss = x1 * x1 + x2 * x2;
#pragma unroll
    for (int d = 32; d; d >>= 1) ss += __shfl_xor(ss, d);
    float r = rsqrtf(ss * (1.0f / 128.0f) + 1e-5f);
    float xn1 = x1 * r * w[lane];
    float xn2 = x2 * r * w[lane + 64];

    float pos = (float)positions[s];
    float inv_freq = exp2f((float)lane * (-13.287712379549449f / 64.0f));
    float f = pos * inv_freq;
    float c = cosf(f), sn = sinf(f);
    float sc = which ? 1.0f : 0.12751863738f;   // q: fold scale*log2(e)
    base[lane]      = f2bf((xn1 * c - xn2 * sn) * sc);
    base[lane + 64] = f2bf((xn2 * c + xn1 * sn) * sc);
  } else if (blockIdx.x < 33792) {
    int bid2 = blockIdx.x - 32768;
    const int h  = bid2 & 31;
    const int kt = bid2 >> 5;
    const int tid = threadIdx.x;
    {
      int rr = tid >> 2;
      int db = (tid & 3) * 32;
      const short* src = qkv + (size_t)(kt * 64 + rr) * QKV_O + 2 * OD + h * HD + db;
#pragma unroll
      for (int i = 0; i < 4; ++i)
        *(bf16x8*)&T[rr][db + i * 8] = *(const bf16x8*)(src + i * 8);
    }
    __syncthreads();
    {
      int d  = tid >> 1;
      int k0 = (tid & 1) * 32;
      short* dst = vtp + (((size_t)h * 32 + kt) * 128 + d) * 64 + k0;
#pragma unroll
      for (int c = 0; c < 4; ++c) {
        bf16x8 v;
#pragma unroll
        for (int j = 0; j < 8; ++j) v[j] = T[k0 + c * 8 + j][d];
        *(bf16x8*)&dst[c * 8] = v;
      }
    }
  } else {
    int i = (blockIdx.x - 33792) * 256 + threadIdx.x;
    if (i >= n3_4) return;
    float4 f = ((const float4*)ow)[i];
    s16x4 s;
    s.x = f2bf(f.x); s.y = f2bf(f.y); s.z = f2bf(f.z); s.w = f2bf(f.w);
    ((s16x4*)ow_bf)[i] = s;
  }
}

// ---------------- flash attention (causal), Bq=64/Bk=64 paired, dbuf + async-stage ------
// r10: XCD-aware head mapping. r9 counters: FETCH 247 MB ~= 8x K/V amplification --
// dim3(16,NH) round-robins the 16 q-blocks of a head across all 8 XCDs, so every XCD
// streams every head's K/V from HBM. New linear grid: xcd = bid&7 (hw round-robin),
// head = xcd*4 + (u>>4), qpair = u&15 -> each XCD owns 4 heads x all 16 q-blocks;
// K/V working set 4 x 1 MB = 4 MB = one XCD L2. Internals byte-identical to r6/r9
// (dbuf, loads-before-barrier, writeKV-after-compute, T5 setprio, T13 defer-max).
__global__ __launch_bounds__(256, 2) void attn_kernel(
    const short* __restrict__ qkv, const short* __restrict__ vtp, short* __restrict__ obuf) {
  __shared__ short Klds[2][64 * 128];   // 2 x 16 KB
  __shared__ short Vt[2][128 * 64];     // 2 x 16 KB
  __shared__ short Plds[4][16 * 64];    // 8 KB

  const int tid  = threadIdx.x;
  const int lane = tid & 63;
  const int wave = tid >> 6;
  const int quad = lane >> 4;
  const int col  = lane & 15;

  // XCD-aware head/qpair mapping (512 blocks, 2/CU, 1 exact round)
  const int bid = blockIdx.x;
  const int xcd = bid & 7;
  const int u   = bid >> 3;            // 0..63
  const int h   = xcd * 4 + (u >> 4);  // 4 heads per XCD
  const int qp  = u & 15;              // q-pair index 0..15

  const int kr  = tid >> 2;
  const int kcb = (tid & 3) * 32;
  const int vd  = tid >> 1;
  const int vcb = (tid & 1) * 32;

  bf16x8 kreg[4], vreg[4];

  auto loadK = [&](int kt) {
    const short* kp = qkv + (size_t)(kt * 64 + kr) * QKV_O + OD + h * HD + kcb;
#pragma unroll
    for (int i = 0; i < 4; ++i) kreg[i] = *(const bf16x8*)(kp + i * 8);
  };
  auto loadV = [&](int kt) {
    const short* vp = vtp + (((size_t)h * 32 + kt) * 128 + vd) * 64 + vcb;
#pragma unroll
    for (int i = 0; i < 4; ++i) vreg[i] = *(const bf16x8*)(vp + i * 8);
  };
  auto writeKV = [&](int buf) {
#pragma unroll
    for (int i = 0; i < 4; ++i) {
      int swz = ((tid & 3) * 4 + i) ^ (kr & 15);
      *(bf16x8*)&Klds[buf][kr * 128 + swz * 8] = kreg[i];
    }
#pragma unroll
    for (int i = 0; i < 4; ++i) {
      int swz = ((tid & 1) * 4 + i) ^ (vd & 7);
      *(bf16x8*)&Vt[buf][vd * 64 + swz * 8] = vreg[i];
    }
  };

#pragma unroll 1
  for (int half = 0; half < 2; ++half) {
    const int qt = half == 0 ? qp : 31 - qp;   // paired: 33 k-iters/block
    const int qbase = qt * 64 + wave * 16;

    bf16x8 qf[4];
#pragma unroll
    for (int kf = 0; kf < 4; ++kf)
      qf[kf] = *(const bf16x8*)(qkv + (size_t)(qbase + col) * QKV_O + h * HD + kf * 32 + quad * 8);

    f32x4 o[8] = {};
    float m_r[4], l_i[4];
#pragma unroll
    for (int r = 0; r < 4; ++r) { m_r[r] = -1e30f; l_i[r] = 0.f; }

    loadK(0); loadV(0);
    __syncthreads();
    writeKV(0);

#pragma unroll 1
    for (int kt = 0; kt <= qt; ++kt) {
      const int cur = kt & 1;
      if (kt < qt) { loadK(kt + 1); loadV(kt + 1); }   // T14: issue early
      __syncthreads();                                  // buf[cur] writes visible

      f32x4 sfr[4];
      __builtin_amdgcn_s_setprio(1);
#pragma unroll
      for (int nf = 0; nf < 4; ++nf) {
        f32x4 acc = {};
#pragma unroll
        for (int kf = 0; kf < 4; ++kf) {
          bf16x8 b = *(const bf16x8*)&Klds[cur][(nf * 16 + col) * 128 + ((kf * 4 + quad) ^ col) * 8];
          acc = __builtin_amdgcn_mfma_f32_16x16x32_bf16(qf[kf], b, acc, 0, 0, 0);
        }
        sfr[nf] = acc;
      }
      __builtin_amdgcn_s_setprio(0);

      if (kt == qt) {
#pragma unroll
        for (int nf = 0; nf < 4; ++nf)
#pragma unroll
          for (int r = 0; r < 4; ++r) {
            int key = kt * 64 + nf * 16 + col;
            int qg  = qbase + quad * 4 + r;
            if (key > qg) sfr[nf][r] = -1e30f;
          }
      }

#pragma unroll
      for (int r = 0; r < 4; ++r) {
        float mt = fmaxf(fmaxf(sfr[0][r], sfr[1][r]), fmaxf(sfr[2][r], sfr[3][r]));
#pragma unroll
        for (int d = 8; d; d >>= 1) mt = fmaxf(mt, __shfl_xor(mt, d));
        float mnew = fmaxf(m_r[r], mt);
        bool defer = __all(mnew - m_r[r] <= 8.0f);
        if (defer) mnew = m_r[r];
        float alpha = exp2f(m_r[r] - mnew);
        float ps = 0.f;
#pragma unroll
        for (int nf = 0; nf < 4; ++nf) {
          float p = exp2f(sfr[nf][r] - mnew);
          sfr[nf][r] = p;
          ps += p;
        }
        l_i[r] = l_i[r] * alpha + ps;
        if (!defer) {
#pragma unroll
          for (int nf = 0; nf < 8; ++nf) o[nf][r] *= alpha;
          m_r[r] = mnew;
        }
      }

#pragma unroll
      for (int nf = 0; nf < 4; ++nf)
#pragma unroll
        for (int r = 0; r < 4; ++r) {
          int row = quad * 4 + r;
          int key = nf * 16 + col;
          Plds[wave][row * 64 + ((key >> 3) ^ (row & 7)) * 8 + (key & 7)] = f2bf(sfr[nf][r]);
        }

      bf16x8 pa[2];
#pragma unroll
      for (int kf = 0; kf < 2; ++kf)
        pa[kf] = *(const bf16x8*)&Plds[wave][col * 64 + ((kf * 4 + quad) ^ (col & 7)) * 8];
      __builtin_amdgcn_s_setprio(1);
#pragma unroll
      for (int nf = 0; nf < 8; ++nf)
#pragma unroll
        for (int kf = 0; kf < 2; ++kf) {
          bf16x8 vb = *(const bf16x8*)&Vt[cur][(nf * 16 + col) * 64 + ((kf * 4 + quad) ^ (col & 7)) * 8];
          o[nf] = __builtin_amdgcn_mfma_f32_16x16x32_bf16(pa[kf], vb, o[nf], 0, 0, 0);
        }
      __builtin_amdgcn_s_setprio(0);

      if (kt < qt) writeKV(cur ^ 1);
    }

#pragma unroll
    for (int r = 0; r < 4; ++r) {
      float lt = l_i[r];
#pragma unroll
      for (int d = 8; d; d >>= 1) lt += __shfl_xor(lt, d);
      float inv = 1.0f / lt;
      int sg = qbase + quad * 4 + r;
#pragma unroll
      for (int nf = 0; nf < 8; ++nf)
        obuf[(size_t)sg * OD + h * HD + nf * 16 + col] = f2bf(o[nf][r] * inv);
    }
  }
}

// ---------------- launcher ----------------
extern "C" void kernel_launch(void* const* d_in, const int* in_sizes, int n_in,
                              void* d_out, int out_size, void* d_ws, size_t ws_size,
                              hipStream_t stream) {
  (void)in_sizes; (void)n_in; (void)out_size;
  const float* hs   = (const float*)d_in[0];
  const int*   pos  = (const int*)d_in[1];
  const float* qkvw = (const float*)d_in[2];
  const float* qw   = (const float*)d_in[3];
  const float* kw   = (const float*)d_in[4];
  const float* ow   = (const float*)d_in[5];
  float* out = (float*)d_out;

  // ws plan: [0,48M) qkvb | [48M,64M) obuf | [64M,112M) qkvw_bf, later ow_bf (fast path)
  char* ws = (char*)d_ws;
  short* qkvb    = (short*)(ws);
  short* obuf    = (short*)(ws + 50331648);
  short* qkvw_bf = (short*)(ws + 67108864);
  short* ow_bf   = (short*)(ws + 67108864);   // reuses qkvw_bf region after GEMM1
  short* hsb  = (short*)d_out;
  short* vtp  = (short*)d_out;

  const bool fast = ws_size >= (size_t)117440512;

  if (fast) {
    // 1) convert hidden_states AND qkv_w -> bf16 in one launch
    int n1 = (S_LEN * HID) / 4, n2 = (QKV_O * HID) / 4;
    convert2_kernel<<<(n1 + n2 + 255) / 256, 256, 0, stream>>>(hs, hsb, n1, qkvw, qkvw_bf, n2);
    // 2) qkv = hs @ qkv_w^T, TWO one-exact-round slices (r9-proven)
    gemm8p<256, 256, 0><<<(S_LEN / 256) * (8192 / 256), 512, 0, stream>>>(
        hsb, qkvw_bf, qkvb, HID, 8192, QKV_O);
    gemm8p<128, 256, 0><<<(S_LEN / 128) * (4096 / 256), 512, 0, stream>>>(
        hsb, qkvw_bf + (size_t)8192 * HID, qkvb + 8192, HID, 4096, QKV_O);
    // 3+4+2b) RMSNorm+RoPE, V pack, AND o_proj convert (into now-dead qkvw_bf), one launch
    int n3 = (HID * OD) / 4;
    normrope_packv_kernel<<<(S_LEN * 2 * NH) / 4 + NH * (S_LEN / 64) + n3 / 256,
                            256, 0, stream>>>(qkvb, pos, qw, kw, vtp, ow, ow_bf, n3);
  } else {
    int n1 = (S_LEN * HID) / 4;
    convert2_kernel<<<(n1 + 255) / 256, 256, 0, stream>>>(hs, hsb, n1, hs, hsb, 0);
    gemm_nt_f32w<128, 0><<<dim3(QKV_O / 128, S_LEN / BM), 256, 0, stream>>>(
        hsb, qkvw, qkvb, HID, QKV_O);
    normrope_packv_kernel<<<(S_LEN * 2 * NH) / 4 + NH * (S_LEN / 64),
                            256, 0, stream>>>(qkvb, pos, qw, kw, vtp, hs, (short*)d_ws, 0);
  }

  // 5) causal flash attention -> obuf (512 blocks, XCD-aware head mapping)
  attn_kernel<<<512, 256, 0, stream>>>(qkvb, vtp, obuf);

  // 6) out = obuf @ o_proj_w^T (fp32 C)
  if (fast) {
    gemm8p<128, 128, 1><<<(S_LEN / 128) * (HID / 128), 512, 0, stream>>>(
        obuf, ow_bf, out, OD, HID, HID);
  } else {
    gemm_nt_f32w<64, 1><<<dim3(HID / 64, S_LEN / BM), 256, 0, stream>>>(
        obuf, ow, out, OD, HID);
  }
}

// Round 11
// 441.468 us; speedup vs baseline: 1.1126x; 1.0515x over previous
//
#include <hip/hip_runtime.h>
#include <cstdint>
#include <cstddef>

// ---- problem constants ----
static constexpr int S_LEN = 2048;
static constexpr int HID   = 2048;
static constexpr int NH    = 32;
static constexpr int HD    = 128;
static constexpr int OD    = 4096;    // NH*HD
static constexpr int QKV_O = 12288;   // 3*OD

#define AS1 __attribute__((address_space(1)))
#define AS3 __attribute__((address_space(3)))

typedef __attribute__((ext_vector_type(8))) short bf16x8;
typedef __attribute__((ext_vector_type(4))) float f32x4;
typedef __attribute__((ext_vector_type(4))) short s16x4;

template <int V> struct IC { static constexpr int v = V; };

__device__ __forceinline__ short f2bf(float f) {
  unsigned u = __float_as_uint(f);
  unsigned r = (u + 0x7fffu + ((u >> 16) & 1u)) >> 16;   // RNE
  return (short)r;
}
__device__ __forceinline__ float bf2f(short s) {
  return __uint_as_float(((unsigned)(unsigned short)s) << 16);
}
// pack two f32 -> two bf16 (truncation) in ONE v_perm: low short = trunc(a), high = trunc(b)
__device__ __forceinline__ unsigned pk2bf(float a, float b) {
  return __builtin_amdgcn_perm(__float_as_uint(b), __float_as_uint(a), 0x07060302u);
}

// ---------------- fp32 -> bf16 convert: two regions in one launch ----------------
__global__ void convert2_kernel(const float* __restrict__ in1, short* __restrict__ out1, int n1_4,
                                const float* __restrict__ in2, short* __restrict__ out2, int n2_4) {
  int i = blockIdx.x * blockDim.x + threadIdx.x;
  const float* in; short* out; int j;
  if (i < n1_4) { in = in1; out = out1; j = i; }
  else { j = i - n1_4; if (j >= n2_4) return; in = in2; out = out2; }
  float4 f = ((const float4*)in)[j];
  s16x4 s;
  s.x = f2bf(f.x); s.y = f2bf(f.y); s.z = f2bf(f.z); s.w = f2bf(f.w);
  ((s16x4*)out)[j] = s;
}

// ========= generic BMt x BNT 8-phase bf16 NT GEMM (r5's PROVEN sync skeleton) =========
// GEMM1 = two one-exact-round slices (r9-proven): <256,256> on N=8192 + <128,256> on
// N=4096. LDS-BW model: ~55.5 B/cyc/CU steady state; exact-round grids avoid the tail.
// Sync skeleton r5/r8-proven; loads/tile L = 2*(BMt/128)+2*BH; vmcnt(L) at ph4/ph8;
// cross-wave certification = per-wave counted wait BEFORE barrier.
// XCD 2D-chunk mapping (requires (N/BNT)%8==0). Granule swizzle g^=(row>>1)&7 via
// inverse-permuted global source (0 bank conflicts r2-r10).
template <int BMt, int BNT, int CMODE>
__global__ __launch_bounds__(512, 2) void gemm8p(
    const short* __restrict__ A, const short* __restrict__ Bw, void* __restrict__ Cp,
    int K, int N, int ldc) {
  constexpr int BH  = BNT / 128;   // B half-tiles (1 or 2)
  constexpr int NJ  = BNT / 64;    // per-wave N frags (2 or 4)
  constexpr int NJH = NJ / 2;      // N frags per quadrant
  constexpr int MF  = BMt / 64;    // per-wave M frags per half (2 or 4)
  constexpr int AST = BMt / 64;    // stA sweeps
  constexpr int LT  = 2 * (BMt / 128) + 2 * BH;   // loads per K-tile
  __shared__ short Al[2][BMt * 64];
  __shared__ short Bl[2][BH][128 * 64];
  const int tid  = threadIdx.x;
  const int lane = tid & 63;
  const int quad = lane >> 4;
  const int col  = lane & 15;
  const int wave = tid >> 6;
  const int wm   = wave >> 2;
  const int wn   = wave & 3;

  // XCD 2D-chunk mapping (requires nbn % 8 == 0)
  const int nbn = N / BNT;
  const int nbm = gridDim.x / nbn;
  const int xcd = blockIdx.x & 7;
  const int u   = blockIdx.x >> 3;
  const int m0  = (u % nbm) * BMt;
  const int n0  = (xcd * (nbn >> 3) + u / nbm) * BNT;

  const int NT = K >> 6;

  f32x4 acc[2 * MF][NJ] = {};
  bf16x8 a[MF][2], b0[NJH][2], b1[NJH][2];

  auto stA = [&](int t, int buf) {
#pragma unroll
    for (int r = 0; r < AST; ++r) {
      int idx = r * 512 + tid;
      int row = idx >> 3;
      int g   = idx & 7;
      int gs  = g ^ ((row >> 1) & 7);
      const short* ga = A + (size_t)(m0 + row) * K + t * 64 + gs * 8;
      __builtin_amdgcn_global_load_lds((const AS1 unsigned*)ga,
                                       (AS3 unsigned*)&Al[buf][idx * 8], 16, 0, 0);
    }
  };
  auto stB = [&](int t, int buf, int h) {
#pragma unroll
    for (int r = 0; r < 2; ++r) {
      int idx = r * 512 + tid;
      int row = idx >> 3;
      int g   = idx & 7;
      int gs  = g ^ ((row >> 1) & 7);
      const short* gb = Bw + (size_t)(n0 + h * 128 + row) * K + t * 64 + gs * 8;
      __builtin_amdgcn_global_load_lds((const AS1 unsigned*)gb,
                                       (AS3 unsigned*)&Bl[buf][h][idx * 8], 16, 0, 0);
    }
  };
  auto rdA = [&](int buf, int mh) {
#pragma unroll
    for (int i = 0; i < MF; ++i) {
      int rh = wm * (BMt / 2) + (mh * MF + i) * 16 + col;
#pragma unroll
      for (int kf = 0; kf < 2; ++kf)
        a[i][kf] =
            *(const bf16x8*)&Al[buf][rh * 64 + (((kf * 4 + quad) ^ ((rh >> 1) & 7)) * 8)];
    }
  };
  auto rdB = [&](int buf, int nh, bf16x8 (&bb)[NJH][2]) {
#pragma unroll
    for (int j = 0; j < NJH; ++j) {
      int br = wn * (BNT / 4) + nh * (BNT / 8) + j * 16 + col;
      int bh = br >> 7, rh = br & 127;
#pragma unroll
      for (int kf = 0; kf < 2; ++kf)
        bb[j][kf] =
            *(const bf16x8*)&Bl[buf][bh][rh * 64 + (((kf * 4 + quad) ^ ((rh >> 1) & 7)) * 8)];
    }
  };
  auto mm = [&](auto MH, auto NHc, bf16x8 (&bb)[NJH][2]) {
    constexpr int mh = MH.v, nh = NHc.v;
    __builtin_amdgcn_s_setprio(1);
#pragma unroll
    for (int i = 0; i < MF; ++i)
#pragma unroll
      for (int j = 0; j < NJH; ++j)
#pragma unroll
        for (int kf = 0; kf < 2; ++kf)
          acc[mh * MF + i][nh * NJH + j] = __builtin_amdgcn_mfma_f32_16x16x32_bf16(
              a[i][kf], bb[j][kf], acc[mh * MF + i][nh * NJH + j], 0, 0, 0);
    __builtin_amdgcn_s_setprio(0);
  };
#define LGK() do { asm volatile("s_waitcnt lgkmcnt(0)"); __builtin_amdgcn_sched_barrier(0); } while (0)
#define BAR() __builtin_amdgcn_s_barrier()
  auto vmc = [] {
    if constexpr (LT == 8)      asm volatile("s_waitcnt vmcnt(8)" ::: "memory");
    else if constexpr (LT == 6) asm volatile("s_waitcnt vmcnt(6)" ::: "memory");
    else                        asm volatile("s_waitcnt vmcnt(4)" ::: "memory");
  };

  // prologue: stage tile0 -> buf0, tile1 -> buf1; retire tile0, keep tile1 in flight
#pragma unroll
  for (int h = 0; h < BH; ++h) stB(0, 0, h);
  stA(0, 0);
#pragma unroll
  for (int h = 0; h < BH; ++h) stB(1, 1, h);
  stA(1, 1);
  vmc();
  BAR();

  for (int i = 0; i < (NT >> 1); ++i) {
    const int t  = 2 * i;
    const int tA = (t + 2 < NT) ? t + 2 : NT - 2;   // clamped restage: identical bytes
    const int tB = (t + 3 < NT) ? t + 3 : NT - 1;
    // ph1
    rdA(0, 0); rdB(0, 0, b0);
    BAR(); LGK();
    mm(IC<0>{}, IC<0>{}, b0);
    BAR();
    // ph2
    rdB(0, 1, b1);
    BAR(); LGK();
    mm(IC<0>{}, IC<1>{}, b1);
    BAR();
    // ph3  (B-buf0 dead since ph2-LGK)
    rdA(0, 1);
    stB(tA, 0, 0);
    BAR(); LGK();
    mm(IC<1>{}, IC<1>{}, b1);
    BAR();
    // ph4  (A-buf0 dead since ph3-LGK)
    if constexpr (BH >= 2) stB(tA, 0, 1);
    stA(tA, 0);
    BAR();
    mm(IC<1>{}, IC<0>{}, b0);
    vmc();
    BAR();
    // ph5
    rdA(1, 0); rdB(1, 0, b0);
    BAR(); LGK();
    mm(IC<0>{}, IC<0>{}, b0);
    BAR();
    // ph6
    rdB(1, 1, b1);
    BAR(); LGK();
    mm(IC<0>{}, IC<1>{}, b1);
    BAR();
    // ph7  (B-buf1 dead since ph6-LGK)
    rdA(1, 1);
    stB(tB, 1, 0);
    if constexpr (BH >= 2) stB(tB, 1, 1);
    BAR(); LGK();
    mm(IC<1>{}, IC<1>{}, b1);
    BAR();
    // ph8  (A-buf1 dead since ph7-LGK)
    stA(tB, 1);
    BAR();
    mm(IC<1>{}, IC<0>{}, b0);
    vmc();
    BAR();
  }
#undef LGK
#undef BAR

  // epilogue: C/D layout col=lane&15, row=quad*4+reg
#pragma unroll
  for (int mi = 0; mi < 2 * MF; ++mi)
#pragma unroll
    for (int nj = 0; nj < NJ; ++nj)
#pragma unroll
      for (int r = 0; r < 4; ++r) {
        int rr = m0 + wm * (BMt / 2) + mi * 16 + quad * 4 + r;
        int cc = n0 + wn * (BNT / 4) + nj * 16 + col;
        if (CMODE == 1)
          ((float*)Cp)[(size_t)rr * ldc + cc] = acc[mi][nj][r];
        else
          ((short*)Cp)[(size_t)rr * ldc + cc] = f2bf(acc[mi][nj][r]);
      }
}

// ---------------- NT GEMM: A(bf16) * B^T(f32) — fallback path only ----------------
#define BM 128
#define BK 32

template <int BNT, int CMODE>
__global__ __launch_bounds__(256, 2) void gemm_nt_f32w(
    const short* __restrict__ A, const float* __restrict__ B, void* __restrict__ Cp,
    int K, int ldc) {
  __shared__ short Alds[2][BM * BK];
  __shared__ short Blds[2][BNT * BK];
  constexpr int WN  = BNT / 2;
  constexpr int NJ  = WN / 16;
  constexpr int BCH = (BNT * 4) / 256;
  const int tid  = threadIdx.x;
  const int lane = tid & 63;
  const int quad = lane >> 4;
  const int col  = lane & 15;
  const int wave = tid >> 6;
  const int m0 = blockIdx.y * BM;
  const int n0 = blockIdx.x * BNT;
  const int wm = (wave & 1) * 64;
  const int wn = (wave >> 1) * WN;

  f32x4 acc[4][NJ] = {};
  float4 breg[BCH][2];

  const int nk = K / BK;

  auto b_issue = [&](int k0) {
#pragma unroll
    for (int it = 0; it < BCH; ++it) {
      int idx = it * 256 + tid;
      int row = idx >> 2;
      int c   = idx & 3;
      const float* gb = B + (size_t)(n0 + row) * K + k0 + c * 8;
      breg[it][0] = *(const float4*)gb;
      breg[it][1] = *(const float4*)(gb + 4);
    }
  };
  auto a_issue = [&](int k0, int buf) {
#pragma unroll
    for (int it = 0; it < 2; ++it) {
      int idx = it * 256 + tid;
      int row = idx >> 2;
      int c   = idx & 3;
      int cs  = c ^ ((row >> 1) & 3);
      const short* ga = A + (size_t)(m0 + row) * K + k0 + cs * 8;
      __builtin_amdgcn_global_load_lds((const AS1 unsigned*)ga,
                                       (AS3 unsigned*)&Alds[buf][idx * 8], 16, 0, 0);
    }
  };
  auto b_write = [&](int buf) {
#pragma unroll
    for (int it = 0; it < BCH; ++it) {
      int idx = it * 256 + tid;
      int row = idx >> 2;
      int c   = idx & 3;
      int cw  = c ^ ((row >> 1) & 3);
      union { unsigned u[4]; bf16x8 v; } pk;
      pk.u[0] = pk2bf(breg[it][0].x, breg[it][0].y);
      pk.u[1] = pk2bf(breg[it][0].z, breg[it][0].w);
      pk.u[2] = pk2bf(breg[it][1].x, breg[it][1].y);
      pk.u[3] = pk2bf(breg[it][1].z, breg[it][1].w);
      *(bf16x8*)&Blds[buf][(row * 4 + cw) * 8] = pk.v;
    }
  };
  auto compute = [&](int buf) {
    bf16x8 a[4], b[NJ];
#pragma unroll
    for (int i = 0; i < 4; ++i) {
      int row = wm + i * 16 + col;
      a[i] = *(const bf16x8*)&Alds[buf][(row * 4 + (quad ^ ((row >> 1) & 3))) * 8];
    }
#pragma unroll
    for (int j = 0; j < NJ; ++j) {
      int row = wn + j * 16 + col;
      b[j] = *(const bf16x8*)&Blds[buf][(row * 4 + (quad ^ ((row >> 1) & 3))) * 8];
    }
#pragma unroll
    for (int i = 0; i < 4; ++i)
#pragma unroll
      for (int j = 0; j < NJ; ++j)
        acc[i][j] = __builtin_amdgcn_mfma_f32_16x16x32_bf16(a[i], b[j], acc[i][j], 0, 0, 0);
  };

  b_issue(0);
  a_issue(0, 0);
  b_write(0);
  __syncthreads();

  for (int t = 0; t < nk - 1; ++t) {
    const int cur = t & 1;
    b_issue((t + 1) * BK);
    a_issue((t + 1) * BK, cur ^ 1);
    compute(cur);
    b_write(cur ^ 1);
    __syncthreads();
  }
  compute((nk - 1) & 1);

#pragma unroll
  for (int i = 0; i < 4; ++i)
#pragma unroll
    for (int j = 0; j < NJ; ++j)
#pragma unroll
      for (int r = 0; r < 4; ++r) {
        int rr = m0 + wm + i * 16 + quad * 4 + r;
        int cc = n0 + wn + j * 16 + col;
        if (CMODE == 1)
          ((float*)Cp)[(size_t)rr * ldc + cc] = acc[i][j][r];
        else
          ((short*)Cp)[(size_t)rr * ldc + cc] = f2bf(acc[i][j][r]);
      }
}

// --- fused: RMSNorm+RoPE q,k [0,32768) + V pack [32768,33792) + o_proj convert [33792,...) ---
__global__ void normrope_packv_kernel(short* __restrict__ qkv,
                                      const int* __restrict__ positions,
                                      const float* __restrict__ qw,
                                      const float* __restrict__ kw,
                                      short* __restrict__ vtp,
                                      const float* __restrict__ ow,
                                      short* __restrict__ ow_bf,
                                      int n3_4) {
  __shared__ short T[64][136];
  if (blockIdx.x < 32768) {
    int item = blockIdx.x * 4 + (threadIdx.x >> 6);
    int lane = threadIdx.x & 63;
    int head  = item & 31;
    int which = (item >> 5) & 1;
    int s     = item >> 6;
    const float* w = which ? kw : qw;
    short* base = qkv + (size_t)s * QKV_O + which * OD + head * HD;

    float x1 = bf2f(base[lane]);
    float x2 = bf2f(base[lane + 64]);
    float ss = x1 * x1 + x2 * x2;
#pragma unroll
    for (int d = 32; d; d >>= 1) ss += __shfl_xor(ss, d);
    float r = rsqrtf(ss * (1.0f / 128.0f) + 1e-5f);
    float xn1 = x1 * r * w[lane];
    float xn2 = x2 * r * w[lane + 64];

    float pos = (float)positions[s];
    float inv_freq = exp2f((float)lane * (-13.287712379549449f / 64.0f));
    float f = pos * inv_freq;
    float c = cosf(f), sn = sinf(f);
    float sc = which ? 1.0f : 0.12751863738f;   // q: fold scale*log2(e)
    base[lane]      = f2bf((xn1 * c - xn2 * sn) * sc);
    base[lane + 64] = f2bf((xn2 * c + xn1 * sn) * sc);
  } else if (blockIdx.x < 33792) {
    int bid2 = blockIdx.x - 32768;
    const int h  = bid2 & 31;
    const int kt = bid2 >> 5;
    const int tid = threadIdx.x;
    {
      int rr = tid >> 2;
      int db = (tid & 3) * 32;
      const short* src = qkv + (size_t)(kt * 64 + rr) * QKV_O + 2 * OD + h * HD + db;
#pragma unroll
      for (int i = 0; i < 4; ++i)
        *(bf16x8*)&T[rr][db + i * 8] = *(const bf16x8*)(src + i * 8);
    }
    __syncthreads();
    {
      int d  = tid >> 1;
      int k0 = (tid & 1) * 32;
      short* dst = vtp + (((size_t)h * 32 + kt) * 128 + d) * 64 + k0;
#pragma unroll
      for (int c = 0; c < 4; ++c) {
        bf16x8 v;
#pragma unroll
        for (int j = 0; j < 8; ++j) v[j] = T[k0 + c * 8 + j][d];
        *(bf16x8*)&dst[c * 8] = v;
      }
    }
  } else {
    int i = (blockIdx.x - 33792) * 256 + threadIdx.x;
    if (i >= n3_4) return;
    float4 f = ((const float4*)ow)[i];
    s16x4 s;
    s.x = f2bf(f.x); s.y = f2bf(f.y); s.z = f2bf(f.z); s.w = f2bf(f.w);
    ((s16x4*)ow_bf)[i] = s;
  }
}

// ---------------- flash attention (causal), Bq=64/Bk=64 paired, dbuf + async-stage ------
// r11: r10 structure (XCD head mapping, dbuf, T14 early loads, T5 setprio) with two
// VALU/latency cuts in the softmax block:
//  (a) partial-max defer vote BEFORE the shfl chain: __all over in-lane partial maxes
//      (lower bound per row) -> skip the 4-deep shfl_xor max chain + rescale in the
//      common case. m stays row-uniform (only updated on the full-reduce path).
//  (b) P-scatter conversion via pk2bf pairs (truncation, like GEMM1's B path):
//      16x 4-op RNE f2bf -> 8x v_perm + 4x shift. Same addresses/writes as r10.
__global__ __launch_bounds__(256, 2) void attn_kernel(
    const short* __restrict__ qkv, const short* __restrict__ vtp, short* __restrict__ obuf) {
  __shared__ short Klds[2][64 * 128];   // 2 x 16 KB
  __shared__ short Vt[2][128 * 64];     // 2 x 16 KB
  __shared__ short Plds[4][16 * 64];    // 8 KB

  const int tid  = threadIdx.x;
  const int lane = tid & 63;
  const int wave = tid >> 6;
  const int quad = lane >> 4;
  const int col  = lane & 15;

  // XCD-aware head/qpair mapping (512 blocks, 2/CU, 1 exact round)
  const int bid = blockIdx.x;
  const int xcd = bid & 7;
  const int u   = bid >> 3;            // 0..63
  const int h   = xcd * 4 + (u >> 4);  // 4 heads per XCD
  const int qp  = u & 15;              // q-pair index 0..15

  const int kr  = tid >> 2;
  const int kcb = (tid & 3) * 32;
  const int vd  = tid >> 1;
  const int vcb = (tid & 1) * 32;

  bf16x8 kreg[4], vreg[4];

  auto loadK = [&](int kt) {
    const short* kp = qkv + (size_t)(kt * 64 + kr) * QKV_O + OD + h * HD + kcb;
#pragma unroll
    for (int i = 0; i < 4; ++i) kreg[i] = *(const bf16x8*)(kp + i * 8);
  };
  auto loadV = [&](int kt) {
    const short* vp = vtp + (((size_t)h * 32 + kt) * 128 + vd) * 64 + vcb;
#pragma unroll
    for (int i = 0; i < 4; ++i) vreg[i] = *(const bf16x8*)(vp + i * 8);
  };
  auto writeKV = [&](int buf) {
#pragma unroll
    for (int i = 0; i < 4; ++i) {
      int swz = ((tid & 3) * 4 + i) ^ (kr & 15);
      *(bf16x8*)&Klds[buf][kr * 128 + swz * 8] = kreg[i];
    }
#pragma unroll
    for (int i = 0; i < 4; ++i) {
      int swz = ((tid & 1) * 4 + i) ^ (vd & 7);
      *(bf16x8*)&Vt[buf][vd * 64 + swz * 8] = vreg[i];
    }
  };

#pragma unroll 1
  for (int half = 0; half < 2; ++half) {
    const int qt = half == 0 ? qp : 31 - qp;   // paired: 33 k-iters/block
    const int qbase = qt * 64 + wave * 16;

    bf16x8 qf[4];
#pragma unroll
    for (int kf = 0; kf < 4; ++kf)
      qf[kf] = *(const bf16x8*)(qkv + (size_t)(qbase + col) * QKV_O + h * HD + kf * 32 + quad * 8);

    f32x4 o[8] = {};
    float m_r[4], l_i[4];
#pragma unroll
    for (int r = 0; r < 4; ++r) { m_r[r] = -1e30f; l_i[r] = 0.f; }

    loadK(0); loadV(0);
    __syncthreads();
    writeKV(0);

#pragma unroll 1
    for (int kt = 0; kt <= qt; ++kt) {
      const int cur = kt & 1;
      if (kt < qt) { loadK(kt + 1); loadV(kt + 1); }   // T14: issue early
      __syncthreads();                                  // buf[cur] writes visible

      f32x4 sfr[4];
      __builtin_amdgcn_s_setprio(1);
#pragma unroll
      for (int nf = 0; nf < 4; ++nf) {
        f32x4 acc = {};
#pragma unroll
        for (int kf = 0; kf < 4; ++kf) {
          bf16x8 b = *(const bf16x8*)&Klds[cur][(nf * 16 + col) * 128 + ((kf * 4 + quad) ^ col) * 8];
          acc = __builtin_amdgcn_mfma_f32_16x16x32_bf16(qf[kf], b, acc, 0, 0, 0);
        }
        sfr[nf] = acc;
      }
      __builtin_amdgcn_s_setprio(0);

      if (kt == qt) {   // diagonal: causal mask
#pragma unroll
        for (int nf = 0; nf < 4; ++nf)
#pragma unroll
          for (int r = 0; r < 4; ++r) {
            int key = kt * 64 + nf * 16 + col;
            int qg  = qbase + quad * 4 + r;
            if (key > qg) sfr[nf][r] = -1e30f;
          }
      }

      // online softmax (log2 domain): partial-max defer vote, full reduce only on fail
#pragma unroll
      for (int r = 0; r < 4; ++r) {
        float pm = fmaxf(fmaxf(sfr[0][r], sfr[1][r]), fmaxf(sfr[2][r], sfr[3][r]));
        if (!__all(pm - m_r[r] <= 8.0f)) {   // rare: true max may exceed m+8
          float mt = pm;
#pragma unroll
          for (int d = 8; d; d >>= 1) mt = fmaxf(mt, __shfl_xor(mt, d));
          float mnew = fmaxf(m_r[r], mt);
          float alpha = exp2f(m_r[r] - mnew);
          l_i[r] *= alpha;
#pragma unroll
          for (int nf = 0; nf < 8; ++nf) o[nf][r] *= alpha;
          m_r[r] = mnew;
        }
        float ps = 0.f;
#pragma unroll
        for (int nf = 0; nf < 4; ++nf) {
          float p = exp2f(sfr[nf][r] - m_r[r]);
          sfr[nf][r] = p;
          ps += p;
        }
        l_i[r] += ps;
      }

      // P -> per-wave LDS (C-layout scatter -> A-layout rows), swizzled; pk2bf pairs
#pragma unroll
      for (int nf = 0; nf < 4; ++nf) {
        unsigned w0 = pk2bf(sfr[nf][0], sfr[nf][1]);
        unsigned w1 = pk2bf(sfr[nf][2], sfr[nf][3]);
        int key = nf * 16 + col;
        int gr  = key >> 3, kl = key & 7;
        int r0  = quad * 4;
        Plds[wave][(r0 + 0) * 64 + ((gr ^ ((r0 + 0) & 7)) * 8) + kl] = (short)w0;
        Plds[wave][(r0 + 1) * 64 + ((gr ^ ((r0 + 1) & 7)) * 8) + kl] = (short)(w0 >> 16);
        Plds[wave][(r0 + 2) * 64 + ((gr ^ ((r0 + 2) & 7)) * 8) + kl] = (short)w1;
        Plds[wave][(r0 + 3) * 64 + ((gr ^ ((r0 + 3) & 7)) * 8) + kl] = (short)(w1 >> 16);
      }

      // O += P V
      bf16x8 pa[2];
#pragma unroll
      for (int kf = 0; kf < 2; ++kf)
        pa[kf] = *(const bf16x8*)&Plds[wave][col * 64 + ((kf * 4 + quad) ^ (col & 7)) * 8];
      __builtin_amdgcn_s_setprio(1);
#pragma unroll
      for (int nf = 0; nf < 8; ++nf)
#pragma unroll
        for (int kf = 0; kf < 2; ++kf) {
          bf16x8 vb = *(const bf16x8*)&Vt[cur][(nf * 16 + col) * 64 + ((kf * 4 + quad) ^ (col & 7)) * 8];
          o[nf] = __builtin_amdgcn_mfma_f32_16x16x32_bf16(pa[kf], vb, o[nf], 0, 0, 0);
        }
      __builtin_amdgcn_s_setprio(0);

      if (kt < qt) writeKV(cur ^ 1);
    }

    // epilogue
#pragma unroll
    for (int r = 0; r < 4; ++r) {
      float lt = l_i[r];
#pragma unroll
      for (int d = 8; d; d >>= 1) lt += __shfl_xor(lt, d);
      float inv = 1.0f / lt;
      int sg = qbase + quad * 4 + r;
#pragma unroll
      for (int nf = 0; nf < 8; ++nf)
        obuf[(size_t)sg * OD + h * HD + nf * 16 + col] = f2bf(o[nf][r] * inv);
    }
  }
}

// ---------------- launcher ----------------
extern "C" void kernel_launch(void* const* d_in, const int* in_sizes, int n_in,
                              void* d_out, int out_size, void* d_ws, size_t ws_size,
                              hipStream_t stream) {
  (void)in_sizes; (void)n_in; (void)out_size;
  const float* hs   = (const float*)d_in[0];
  const int*   pos  = (const int*)d_in[1];
  const float* qkvw = (const float*)d_in[2];
  const float* qw   = (const float*)d_in[3];
  const float* kw   = (const float*)d_in[4];
  const float* ow   = (const float*)d_in[5];
  float* out = (float*)d_out;

  // ws plan: [0,48M) qkvb | [48M,64M) obuf | [64M,112M) qkvw_bf, later ow_bf (fast path)
  char* ws = (char*)d_ws;
  short* qkvb    = (short*)(ws);
  short* obuf    = (short*)(ws + 50331648);
  short* qkvw_bf = (short*)(ws + 67108864);
  short* ow_bf   = (short*)(ws + 67108864);   // reuses qkvw_bf region after GEMM1
  short* hsb  = (short*)d_out;
  short* vtp  = (short*)d_out;

  const bool fast = ws_size >= (size_t)117440512;

  if (fast) {
    // 1) convert hidden_states AND qkv_w -> bf16 in one launch
    int n1 = (S_LEN * HID) / 4, n2 = (QKV_O * HID) / 4;
    convert2_kernel<<<(n1 + n2 + 255) / 256, 256, 0, stream>>>(hs, hsb, n1, qkvw, qkvw_bf, n2);
    // 2) qkv = hs @ qkv_w^T, TWO one-exact-round slices (r9-proven)
    gemm8p<256, 256, 0><<<(S_LEN / 256) * (8192 / 256), 512, 0, stream>>>(
        hsb, qkvw_bf, qkvb, HID, 8192, QKV_O);
    gemm8p<128, 256, 0><<<(S_LEN / 128) * (4096 / 256), 512, 0, stream>>>(
        hsb, qkvw_bf + (size_t)8192 * HID, qkvb + 8192, HID, 4096, QKV_O);
    // 3+4+2b) RMSNorm+RoPE, V pack, AND o_proj convert (into now-dead qkvw_bf), one launch
    int n3 = (HID * OD) / 4;
    normrope_packv_kernel<<<(S_LEN * 2 * NH) / 4 + NH * (S_LEN / 64) + n3 / 256,
                            256, 0, stream>>>(qkvb, pos, qw, kw, vtp, ow, ow_bf, n3);
  } else {
    int n1 = (S_LEN * HID) / 4;
    convert2_kernel<<<(n1 + 255) / 256, 256, 0, stream>>>(hs, hsb, n1, hs, hsb, 0);
    gemm_nt_f32w<128, 0><<<dim3(QKV_O / 128, S_LEN / BM), 256, 0, stream>>>(
        hsb, qkvw, qkvb, HID, QKV_O);
    normrope_packv_kernel<<<(S_LEN * 2 * NH) / 4 + NH * (S_LEN / 64),
                            256, 0, stream>>>(qkvb, pos, qw, kw, vtp, hs, (short*)d_ws, 0);
  }

  // 5) causal flash attention -> obuf (512 blocks, XCD-aware head mapping)
  attn_kernel<<<512, 256, 0, stream>>>(qkvb, vtp, obuf);

  // 6) out = obuf @ o_proj_w^T (fp32 C)
  if (fast) {
    gemm8p<128, 128, 1><<<(S_LEN / 128) * (HID / 128), 512, 0, stream>>>(
        obuf, ow_bf, out, OD, HID, HID);
  } else {
    gemm_nt_f32w<64, 1><<<dim3(HID / 64, S_LEN / BM), 256, 0, stream>>>(
        obuf, ow, out, OD, HID);
  }
}